// Round 1
// baseline (1725.807 us; speedup 1.0000x reference)
//
#include <hip/hip_runtime.h>
#include <hip/hip_bf16.h>

// DNBN system, fp32 baseline.
// N=8 experts, B=256, M=512, C=512, NH=8, DH=64, S=8, HC=64, T=3, OUT=100.
// Key simplification: T(3) < S(8) so FIFO never evicts -> buf.mean == msum/8.

#define NEXP 8
#define BB   256
#define MM   512
#define CC   512
#define HC   64
#define TT   3
#define OUTD 100

// ---------------- conv1: x[256,3,32,32] -> h1[e,256,64,16,16], stride2 SAME(pad lo=0,hi=1), relu
__global__ __launch_bounds__(256) void conv1_kernel(
    const float* __restrict__ x, const float* __restrict__ w1,
    const float* __restrict__ b1, float* __restrict__ h1c, int n0)
{
  __shared__ float xs[3072];
  __shared__ float wsh[1728];
  int b = blockIdx.x, e = blockIdx.y, n = n0 + e, t = threadIdx.x;
  const float* xb = x + (long)b * 3072;
  const float* wn = w1 + (long)n * 1728;
  for (int i = t; i < 3072; i += 256) xs[i] = xb[i];
  for (int i = t; i < 1728; i += 256) wsh[i] = wn[i];
  __syncthreads();
  int oy = t >> 4, ox = t & 15;
  float xv[27];
#pragma unroll
  for (int ci = 0; ci < 3; ci++)
#pragma unroll
    for (int ky = 0; ky < 3; ky++) {
      int iy = oy * 2 + ky;
#pragma unroll
      for (int kx = 0; kx < 3; kx++) {
        int ix = ox * 2 + kx;
        xv[ci * 9 + ky * 3 + kx] = (iy < 32 && ix < 32) ? xs[ci * 1024 + iy * 32 + ix] : 0.f;
      }
    }
  float* ob = h1c + ((long)e * 256 + b) * 16384;
  const float* bn = b1 + n * 64;
  for (int co = 0; co < 64; co++) {
    const float* wp = &wsh[co * 27];
    float acc = bn[co];
#pragma unroll
    for (int q = 0; q < 27; q++) acc = fmaf(xv[q], wp[q], acc);
    ob[co * 256 + t] = fmaxf(acc, 0.f);
  }
}

// ---------------- conv2 as implicit GEMM: [128co x 576k] x [576k x 128col(2b x 64sp)]
__global__ __launch_bounds__(256) void conv2_kernel(
    const float* __restrict__ h1c, const float* __restrict__ w2,
    const float* __restrict__ b2, float* __restrict__ h2, int n0)
{
  __shared__ float As[16][128];
  __shared__ float Xs[16][128];
  int e = blockIdx.y, n = n0 + e, t = threadIdx.x;
  int b0 = blockIdx.x * 2;
  const float* h1b = h1c + (long)e * 4194304;
  const float* wn = w2 + (long)n * 73728;
  float acc[8][8];
#pragma unroll
  for (int i = 0; i < 8; i++)
#pragma unroll
    for (int j = 0; j < 8; j++) acc[i][j] = 0.f;
  int tr = t >> 4, tc = t & 15;
  int ma = t >> 1, ka = (t & 1) * 8;
  int kq = t >> 4, c0 = (t & 15) * 8;
  for (int kt = 0; kt < 36; kt++) {
    int k0 = kt * 16;
    const float* ap = wn + (long)ma * 576 + k0 + ka;
    float4 av0 = *(const float4*)ap;
    float4 av1 = *(const float4*)(ap + 4);
    int kA = k0 + kq;
    int ci = kA / 9; int e9 = kA - ci * 9; int ky = e9 / 3, kx = e9 - ky * 3;
    float xv[8];
#pragma unroll
    for (int j = 0; j < 8; j++) {
      int col = c0 + j;
      int bb = col >> 6, sp = col & 63;
      int iy = (sp >> 3) * 2 + ky, ix = (sp & 7) * 2 + kx;
      xv[j] = (iy < 16 && ix < 16) ? h1b[((long)(b0 + bb)) * 16384 + ci * 256 + iy * 16 + ix] : 0.f;
    }
    __syncthreads();
    As[ka + 0][ma] = av0.x; As[ka + 1][ma] = av0.y; As[ka + 2][ma] = av0.z; As[ka + 3][ma] = av0.w;
    As[ka + 4][ma] = av1.x; As[ka + 5][ma] = av1.y; As[ka + 6][ma] = av1.z; As[ka + 7][ma] = av1.w;
    *(float4*)&Xs[kq][c0]     = make_float4(xv[0], xv[1], xv[2], xv[3]);
    *(float4*)&Xs[kq][c0 + 4] = make_float4(xv[4], xv[5], xv[6], xv[7]);
    __syncthreads();
#pragma unroll
    for (int kk = 0; kk < 16; kk++) {
      float a[8], xx[8];
      *(float4*)&a[0] = *(const float4*)&As[kk][tr * 8];
      *(float4*)&a[4] = *(const float4*)&As[kk][tr * 8 + 4];
      *(float4*)&xx[0] = *(const float4*)&Xs[kk][tc * 8];
      *(float4*)&xx[4] = *(const float4*)&Xs[kk][tc * 8 + 4];
#pragma unroll
      for (int i = 0; i < 8; i++)
#pragma unroll
        for (int j = 0; j < 8; j++) acc[i][j] = fmaf(a[i], xx[j], acc[i][j]);
    }
  }
  const float* bn = b2 + n * 128;
#pragma unroll
  for (int i = 0; i < 8; i++) {
    int co = tr * 8 + i;
    float bi = bn[co];
#pragma unroll
    for (int j = 0; j < 8; j += 4) {
      int col = tc * 8 + j;
      int bb = col >> 6, sp = col & 63;
      float4 v;
      v.x = fmaxf(acc[i][j + 0] + bi, 0.f);
      v.y = fmaxf(acc[i][j + 1] + bi, 0.f);
      v.z = fmaxf(acc[i][j + 2] + bi, 0.f);
      v.w = fmaxf(acc[i][j + 3] + bi, 0.f);
      *(float4*)&h2[(((long)n * 256 + b0 + bb) * 128 + co) * 64 + sp] = v;
    }
  }
}

// ---------------- spatial sum (mean folded into feats gemm via scaleA=1/64)
__global__ __launch_bounds__(256) void pool_kernel(const float* __restrict__ h2, float* __restrict__ pooled)
{
  int o = blockIdx.x * 256 + threadIdx.x; // 262144 outputs
  const float4* p = (const float4*)(h2 + (long)o * 64);
  float s = 0.f;
#pragma unroll
  for (int i = 0; i < 16; i++) { float4 v = p[i]; s += v.x + v.y + v.z + v.w; }
  pooled[o] = s;
}

// ---------------- generic segmented fp32 GEMM, 128xBN tile, 8x(BN/16) per thread
struct Segs {
  const float* B[4];
  const float* bias[4];
  long sB[4];
  long sBias[4];
  int ldb[4];
  int segCols[4];
  int act[4]; // 0 none, 1 relu, 2 sigmoid, 3 tanh
};

template <int BNv>
__global__ __launch_bounds__(256) void gemm_kernel(
    const float* __restrict__ A, Segs segs, float* __restrict__ C, float* __restrict__ Caux,
    int K, int lda, int ldc, long sA, long sC, float scaleA, int auxMode)
{
  constexpr int TW = BNv / 16;
  int z = blockIdx.z;
  int rowBase = blockIdx.y * 128;
  int vcBase = blockIdx.x * BNv;
  int seg = vcBase >> 9;
  int lcolBase = vcBase & 511;
  const float* Bn = segs.B[seg] + (long)z * segs.sB[seg];
  const float* biasN = segs.bias[seg] ? segs.bias[seg] + (long)z * segs.sBias[seg] : nullptr;
  int ldb = segs.ldb[seg];
  int segCols = segs.segCols[seg];
  int act = segs.act[seg];
  const float* An = A + (long)z * sA;
  float* Cn = C + (long)z * sC;
  float* CauxN = Caux ? Caux + (long)z * sC : nullptr;

  __shared__ float As[16][128];
  __shared__ float Bs[16][BNv];
  int t = threadIdx.x;
  int tr = t >> 4, tc = t & 15;
  float acc[8][TW];
#pragma unroll
  for (int i = 0; i < 8; i++)
#pragma unroll
    for (int j = 0; j < TW; j++) acc[i][j] = 0.f;
  int ma = t >> 1, ka = (t & 1) * 8;
  int kb = t >> 4, cb = (t & 15) * TW;
  int nkt = K >> 4;
  for (int kt = 0; kt < nkt; kt++) {
    int k0 = kt << 4;
    const float* ap = An + (long)(rowBase + ma) * lda + k0 + ka;
    float4 av0 = *(const float4*)ap;
    float4 av1 = *(const float4*)(ap + 4);
    float bv[TW];
    const float* bp = Bn + (long)(k0 + kb) * ldb + lcolBase + cb;
    if (lcolBase + cb + TW <= segCols) {
#pragma unroll
      for (int j = 0; j < TW; j += 4) *(float4*)&bv[j] = *(const float4*)(bp + j);
    } else {
#pragma unroll
      for (int j = 0; j < TW; j++) bv[j] = (lcolBase + cb + j < segCols) ? bp[j] : 0.f;
    }
    __syncthreads();
    As[ka + 0][ma] = av0.x * scaleA; As[ka + 1][ma] = av0.y * scaleA;
    As[ka + 2][ma] = av0.z * scaleA; As[ka + 3][ma] = av0.w * scaleA;
    As[ka + 4][ma] = av1.x * scaleA; As[ka + 5][ma] = av1.y * scaleA;
    As[ka + 6][ma] = av1.z * scaleA; As[ka + 7][ma] = av1.w * scaleA;
#pragma unroll
    for (int j = 0; j < TW; j += 4) *(float4*)&Bs[kb][cb + j] = *(const float4*)&bv[j];
    __syncthreads();
#pragma unroll
    for (int kk = 0; kk < 16; kk++) {
      float a[8], bbv[TW];
      *(float4*)&a[0] = *(const float4*)&As[kk][tr * 8];
      *(float4*)&a[4] = *(const float4*)&As[kk][tr * 8 + 4];
#pragma unroll
      for (int j = 0; j < TW; j += 4) *(float4*)&bbv[j] = *(const float4*)&Bs[kk][tc * TW + j];
#pragma unroll
      for (int i = 0; i < 8; i++)
#pragma unroll
        for (int j = 0; j < TW; j++) acc[i][j] = fmaf(a[i], bbv[j], acc[i][j]);
    }
  }
#pragma unroll
  for (int i = 0; i < 8; i++) {
    int r = rowBase + tr * 8 + i;
#pragma unroll
    for (int j = 0; j < TW; j++) {
      int vc = vcBase + tc * TW + j;
      int lc = vc - (seg << 9);
      if (lc < segCols) {
        float vv = acc[i][j];
        if (biasN) vv += biasN[lc];
        if (act == 1) vv = fmaxf(vv, 0.f);
        else if (act == 2) vv = 1.f / (1.f + __expf(-vv));
        else if (act == 3) vv = tanhf(vv);
        long idx = (long)r * ldc + vc;
        Cn[idx] = vv;
        if (auxMode == 1) CauxN[idx] += vv;
        else if (auxMode == 2) CauxN[idx] = vv;
      }
    }
  }
}

// ---------------- GRU controller + send/recv/ab gates; one (n,b) per 64-thread block
__global__ __launch_bounds__(64) void gru_kernel(
    const float* __restrict__ qkv, const float* __restrict__ wh, const float* __restrict__ bh,
    float* __restrict__ cs, const float* __restrict__ sw, const float* __restrict__ sb,
    const float* __restrict__ rw, const float* __restrict__ rb,
    const float* __restrict__ aw, const float* __restrict__ abb,
    float* __restrict__ send, float* __restrict__ recv, float* __restrict__ ab)
{
  int b = blockIdx.x, n = blockIdx.y, hc = threadIdx.x;
  __shared__ float csh[64];
  long nb = (long)n * 256 + b;
  float c0 = cs[nb * 64 + hc];
  csh[hc] = c0;
  __syncthreads();
  const float* whn = wh + (long)n * 64 * 192;
  float g0 = bh[n * 192 + hc], g1 = bh[n * 192 + 64 + hc], g2 = bh[n * 192 + 128 + hc];
  for (int k = 0; k < 64; k++) {
    float cv = csh[k];
    g0 = fmaf(cv, whn[k * 192 + hc], g0);
    g1 = fmaf(cv, whn[k * 192 + 64 + hc], g1);
    g2 = fmaf(cv, whn[k * 192 + 128 + hc], g2);
  }
  const float* gi = qkv + nb * 1728 + 1536; // ctrl_bi already added in gemm
  float iz = gi[hc], ir = gi[64 + hc], inn = gi[128 + hc];
  float zg = 1.f / (1.f + __expf(-(iz + g0)));
  float rg = 1.f / (1.f + __expf(-(ir + g1)));
  float ng = tanhf(inn + rg * g2);
  float cn = (1.f - zg) * ng + zg * c0;
  cs[nb * 64 + hc] = cn;
  float ps = cn * sw[n * 64 + hc];
  float pr = cn * rw[n * 64 + hc];
#pragma unroll
  for (int o = 32; o; o >>= 1) { ps += __shfl_xor(ps, o); pr += __shfl_xor(pr, o); }
  if (hc == 0) {
    send[n * 256 + b] = 1.f / (1.f + __expf(-(ps + sb[n])));
    recv[n * 256 + b] = 1.f / (1.f + __expf(-(pr + rb[n])));
  }
#pragma unroll
  for (int kk = 0; kk < 8; kk++) {
    float pa = cn * aw[(n * 64 + hc) * 8 + kk];
#pragma unroll
    for (int o = 32; o; o >>= 1) pa += __shfl_xor(pa, o);
    if (hc == 0) ab[nb * 8 + kk] = pa + abb[n * 8 + kk];
  }
}

// ---------------- 8-node graph attention, one batch element per block
__global__ __launch_bounds__(256) void attn_kernel(
    const float* __restrict__ qkv, const float* __restrict__ edge,
    const float* __restrict__ send, const float* __restrict__ recv,
    const float* __restrict__ ab, float* __restrict__ msg)
{
  int b = blockIdx.x, t = threadIdx.x;
  __shared__ float qs[8 * 520], ks[8 * 520], vs[8 * 520]; // [n][h(65-pad)][d]
  __shared__ float sc[512]; // [i][j][h]
  __shared__ float se[8], re[8], edg[64], abl[64];
  for (int i = t; i < 4096; i += 256) {
    int nn = i >> 9, c = i & 511, h = c >> 6, d = c & 63;
    long base = ((long)nn * 256 + b) * 1728 + c;
    int la = nn * 520 + h * 65 + d;
    qs[la] = qkv[base];
    ks[la] = qkv[base + 512];
    vs[la] = qkv[base + 1024];
  }
  if (t < 8) { se[t] = send[t * 256 + b]; re[t] = recv[t * 256 + b]; }
  if (t >= 64 && t < 128) edg[t - 64] = edge[t - 64];
  if (t >= 128 && t < 192) { int q = t - 128; abl[q] = ab[((long)(q >> 3) * 256 + b) * 8 + (q & 7)]; }
  __syncthreads();
  for (int idx = t; idx < 512; idx += 256) {
    int i = idx >> 6, j = (idx >> 3) & 7, h = idx & 7;
    const float* qp = &qs[i * 520 + h * 65];
    const float* kp = &ks[j * 520 + h * 65];
    float s = 0.f;
#pragma unroll
    for (int d = 0; d < 64; d++) s = fmaf(qp[d], kp[d], s);
    sc[idx] = s * 0.125f + edg[i * 8 + j] + abl[i * 8 + h];
  }
  __syncthreads();
  if (t < 64) {
    int i = t >> 3, h = t & 7;
    float mx = -1e30f;
#pragma unroll
    for (int j = 0; j < 8; j++) mx = fmaxf(mx, sc[(i << 6) + (j << 3) + h]);
    float e[8], sm = 0.f;
#pragma unroll
    for (int j = 0; j < 8; j++) { e[j] = __expf(sc[(i << 6) + (j << 3) + h] - mx); sm += e[j]; }
    float inv = re[i] / sm;
#pragma unroll
    for (int j = 0; j < 8; j++) sc[(i << 6) + (j << 3) + h] = e[j] * inv * se[j];
  }
  __syncthreads();
  for (int idx = t; idx < 4096; idx += 256) {
    int i = idx >> 9, c = idx & 511, h = c >> 6, d = c & 63;
    float s = 0.f;
#pragma unroll
    for (int j = 0; j < 8; j++) s = fmaf(sc[(i << 6) + (j << 3) + h], vs[j * 520 + h * 65 + d], s);
    msg[((long)i * 256 + b) * 512 + c] = s;
  }
}

// ---------------- h = (1-g)*h + g*cand  (h lives in cat[:, :, 0:512])
__global__ __launch_bounds__(256) void hupdate_kernel(float* __restrict__ cat, const float* __restrict__ gc)
{
  int idx = blockIdx.x * 256 + threadIdx.x; // 1048576
  int nb = idx >> 9, m = idx & 511;
  float g = gc[(long)nb * 1024 + m];
  float cd = gc[(long)nb * 1024 + 512 + m];
  float* hp = cat + (long)nb * 1536 + m;
  *hp = (1.f - g) * (*hp) + g * cd;
}

// ---------------- classifier: [8,256,512] x [512,100] + bias -> d_out
__global__ __launch_bounds__(256) void cls_kernel(
    const float* __restrict__ cat, const float* __restrict__ wcls,
    const float* __restrict__ bcls, float* __restrict__ out)
{
  __shared__ float As[2][512];
  int n = blockIdx.x >> 7, r0 = (blockIdx.x & 127) * 2;
  int t = threadIdx.x;
  for (int i = t; i < 1024; i += 256)
    As[i >> 9][i & 511] = cat[((long)(n * 256 + r0 + (i >> 9))) * 1536 + (i & 511)];
  __syncthreads();
  int r = r0 + (t >> 7), c = t & 127;
  if (c < 100) {
    const float* wp = wcls + (long)n * 512 * 100 + c;
    const float* arow = As[t >> 7];
    float acc = bcls[n * 100 + c];
#pragma unroll 4
    for (int k = 0; k < 512; k++) acc = fmaf(arow[k], wp[k * 100], acc);
    out[((long)(n * 256 + r)) * 100 + c] = acc;
  }
}

extern "C" void kernel_launch(void* const* d_in, const int* in_sizes, int n_in,
                              void* d_out, int out_size, void* d_ws, size_t ws_size,
                              hipStream_t stream)
{
  (void)in_sizes; (void)n_in; (void)out_size;
  const float* x        = (const float*)d_in[0];
  const float* conv1_w  = (const float*)d_in[1];
  const float* conv1_b  = (const float*)d_in[2];
  const float* conv2_w  = (const float*)d_in[3];
  const float* conv2_b  = (const float*)d_in[4];
  const float* feat_w   = (const float*)d_in[5];
  const float* feat_b   = (const float*)d_in[6];
  const float* ctrl_wi  = (const float*)d_in[7];
  const float* ctrl_wh  = (const float*)d_in[8];
  const float* ctrl_bi  = (const float*)d_in[9];
  const float* ctrl_bh  = (const float*)d_in[10];
  const float* send_w   = (const float*)d_in[11];
  const float* send_b   = (const float*)d_in[12];
  const float* recv_w   = (const float*)d_in[13];
  const float* recv_b   = (const float*)d_in[14];
  const float* abias_w  = (const float*)d_in[15];
  const float* abias_b  = (const float*)d_in[16];
  const float* wq       = (const float*)d_in[17];
  const float* wk       = (const float*)d_in[18];
  const float* wv       = (const float*)d_in[19];
  const float* wo       = (const float*)d_in[20];
  const float* bo       = (const float*)d_in[21];
  const float* edge     = (const float*)d_in[22];
  const float* wr       = (const float*)d_in[23];
  const float* br       = (const float*)d_in[24];
  const float* wg       = (const float*)d_in[25];
  const float* bg       = (const float*)d_in[26];
  const float* wc       = (const float*)d_in[27];
  const float* bc       = (const float*)d_in[28];
  const float* wcls     = (const float*)d_in[29];
  const float* bcls     = (const float*)d_in[30];

  // workspace layout (floats)
  float* ws = (float*)d_ws;
  float* h1c    = ws;                    // [4e][256][64*16*16] = 16,777,216
  float* h2     = ws + 16777216;         // [8][256][128][64]   = 16,777,216
  float* pooled = ws + 33554432;         // [8][256][128]       = 262,144
  float* cat    = ws + 33816576;         // [8][256][1536] h|feats|readout = 3,145,728
  float* cs     = ws + 36962304;         // [8][256][64]        = 131,072
  float* qkvb   = ws + 37093376;         // [8][256][1728] q|k|v|gi = 3,538,944
  float* sendb  = ws + 40632320;         // [8][256]
  float* recvb  = ws + 40634368;         // [8][256]
  float* abb    = ws + 40636416;         // [8][256][8]
  float* msg    = ws + 40652800;         // [8][256][512]
  float* msg2   = ws + 41701376;         // [8][256][512]
  float* msum   = ws + 42749952;         // [8][256][512]
  float* gc     = ws + 43798528;         // [8][256][1024] g|cand
  // total = 45,895,680 floats = 183.6 MB
  if (ws_size < 45895680ull * 4ull) return; // workspace too small: bail (output stays zero)

  hipMemsetAsync(cs, 0, 131072 * 4, stream);
  hipMemsetAsync(msum, 0, 1048576 * 4, stream);

  // conv chain in 2 chunks of 4 experts (bounds ws at ~184MB)
  for (int chunk = 0; chunk < 2; chunk++) {
    int n0 = chunk * 4;
    conv1_kernel<<<dim3(256, 4), 256, 0, stream>>>(x, conv1_w, conv1_b, h1c, n0);
    conv2_kernel<<<dim3(128, 4), 256, 0, stream>>>(h1c, conv2_w, conv2_b, h2, n0);
  }
  pool_kernel<<<1024, 256, 0, stream>>>(h2, pooled);

  // feats = relu(pooled/64 @ feat_w + feat_b) -> cat[:,512:1024]; copy -> h slice cat[:,0:512]
  {
    Segs s{};
    s.B[0] = feat_w; s.bias[0] = feat_b; s.ldb[0] = 512;
    s.sB[0] = 128 * 512; s.sBias[0] = 512; s.segCols[0] = 512; s.act[0] = 1;
    gemm_kernel<64><<<dim3(8, 2, 8), 256, 0, stream>>>(
        pooled, s, cat + 512, cat, 128, 128, 1536, 32768L, 393216L, 1.f / 64.f, 2);
  }

  for (int step = 0; step < TT; step++) {
    // fused q|k|v|gi GEMM: virtual cols 1728
    {
      Segs s{};
      s.B[0] = wq; s.B[1] = wk; s.B[2] = wv; s.B[3] = ctrl_wi;
      s.bias[3] = ctrl_bi; s.sBias[3] = 192;
      s.ldb[0] = 512; s.ldb[1] = 512; s.ldb[2] = 512; s.ldb[3] = 192;
      s.sB[0] = 262144; s.sB[1] = 262144; s.sB[2] = 262144; s.sB[3] = 98304;
      s.segCols[0] = 512; s.segCols[1] = 512; s.segCols[2] = 512; s.segCols[3] = 192;
      gemm_kernel<128><<<dim3(14, 2, 8), 256, 0, stream>>>(
          cat, s, qkvb, nullptr, 512, 1536, 1728, 393216L, 442368L, 1.f, 0);
    }
    gru_kernel<<<dim3(256, 8), 64, 0, stream>>>(
        qkvb, ctrl_wh, ctrl_bh, cs, send_w, send_b, recv_w, recv_b,
        abias_w, abias_b, sendb, recvb, abb);
    attn_kernel<<<256, 256, 0, stream>>>(qkvb, edge, sendb, recvb, abb, msg);
    // msg2 = msg @ wo + bo; msum += msg2
    {
      Segs s{};
      s.B[0] = wo; s.bias[0] = bo; s.ldb[0] = 512;
      s.sB[0] = 262144; s.sBias[0] = 512; s.segCols[0] = 512;
      gemm_kernel<64><<<dim3(8, 2, 8), 256, 0, stream>>>(
          msg, s, msg2, msum, 512, 512, 512, 131072L, 131072L, 1.f, 1);
    }
    // readout = (msum/8) @ wr + br -> cat[:,1024:1536]
    {
      Segs s{};
      s.B[0] = wr; s.bias[0] = br; s.ldb[0] = 512;
      s.sB[0] = 262144; s.sBias[0] = 512; s.segCols[0] = 512;
      gemm_kernel<64><<<dim3(8, 2, 8), 256, 0, stream>>>(
          msum, s, cat + 1024, nullptr, 512, 512, 1536, 131072L, 393216L, 0.125f, 0);
    }
    // g|cand = sigmoid/tanh(cat @ [wg|wc] + [bg|bc]), K=1536
    {
      Segs s{};
      s.B[0] = wg; s.B[1] = wc; s.bias[0] = bg; s.bias[1] = bc;
      s.ldb[0] = 512; s.ldb[1] = 512;
      s.sB[0] = 786432; s.sB[1] = 786432; s.sBias[0] = 512; s.sBias[1] = 512;
      s.segCols[0] = 512; s.segCols[1] = 512; s.act[0] = 2; s.act[1] = 3;
      gemm_kernel<64><<<dim3(16, 2, 8), 256, 0, stream>>>(
          cat, s, gc, nullptr, 1536, 1536, 1024, 393216L, 262144L, 1.f, 0);
    }
    hupdate_kernel<<<4096, 256, 0, stream>>>(cat, gc);
  }
  cls_kernel<<<1024, 256, 0, stream>>>(cat, wcls, bcls, (float*)d_out);
}

// Round 2
// 521.943 us; speedup vs baseline: 3.3065x; 3.3065x over previous
//
#include <hip/hip_runtime.h>
#include <hip/hip_bf16.h>

// DNBN system, f16-MFMA version.
// N=8 experts, B=256, M=512, C=512, NH=8, DH=64, S=8, HC=64, T=3, OUT=100.
// T(3) < S(8) so FIFO never evicts -> buf.mean == msum/8.
// Precision plan: GEMMs in f16 MFMA (fp32 accum); h-state, GRU, attention,
// gates, classifier stay fp32.

typedef _Float16 f16;
typedef _Float16 f16x8 __attribute__((ext_vector_type(8)));
typedef float f32x4 __attribute__((ext_vector_type(4)));

#define GLOAD_LDS16(gsrc, ldst)                                                   \
  __builtin_amdgcn_global_load_lds(                                               \
      (const __attribute__((address_space(1))) void*)(gsrc),                      \
      (__attribute__((address_space(3))) void*)(ldst), 16, 0, 0)

// ---------------- transpose+convert: src [8][K][N] f32 -> dst [8][N][K] f16 (scaled)
__global__ __launch_bounds__(256) void twconv_kernel(
    const float* __restrict__ src, f16* __restrict__ dst, int K, int N, float scale)
{
  __shared__ float tile[32][33];
  int z = blockIdx.z;
  int n0 = blockIdx.x * 32, k0 = blockIdx.y * 32;
  int tx = threadIdx.x & 31, ty = threadIdx.x >> 5;
  const float* s = src + (long)z * K * N;
  f16* d = dst + (long)z * N * K;
  for (int r = ty; r < 32; r += 8) {
    int k = k0 + r, n = n0 + tx;
    tile[r][tx] = (k < K && n < N) ? s[(long)k * N + n] : 0.f;
  }
  __syncthreads();
  for (int r = ty; r < 32; r += 8) {
    int n = n0 + r, k = k0 + tx;
    if (n < N && k < K) d[(long)n * K + k] = (f16)(tile[tx][r] * scale);
  }
}

// ---------------- conv2 weight permute: [8][128co][64ci][3][3] -> [8][128co][9tap][64ci] f16
__global__ __launch_bounds__(256) void c2wconv_kernel(const float* __restrict__ src, f16* __restrict__ dst)
{
  long i = (long)blockIdx.x * 256 + threadIdx.x; // 8*128*9*64 = 589824
  int ci = i & 63; long r = i >> 6; int tap = r % 9; r /= 9; int co = r & 127; int n = (int)(r >> 7);
  dst[i] = (f16)src[(((long)(n * 128 + co) * 64 + ci) * 9) + tap];
}

// ---------------- conv1: x[256,3,32,32] -> h1T[e,256,17,17,64] f16 (zero guard ring), relu
__global__ __launch_bounds__(256) void conv1_kernel(
    const float* __restrict__ x, const float* __restrict__ w1,
    const float* __restrict__ b1, f16* __restrict__ h1T)
{
  __shared__ float xs[3072];
  __shared__ float wsh[1728];
  int b = blockIdx.x, n = blockIdx.y, t = threadIdx.x;
  const float* xb = x + (long)b * 3072;
  const float* wn = w1 + (long)n * 1728;
  for (int i = t; i < 3072; i += 256) xs[i] = xb[i];
  for (int i = t; i < 1728; i += 256) wsh[i] = wn[i];
  __syncthreads();
  int oy = t >> 4, ox = t & 15;
  float xv[27];
#pragma unroll
  for (int ci = 0; ci < 3; ci++)
#pragma unroll
    for (int ky = 0; ky < 3; ky++) {
      int iy = oy * 2 + ky;
#pragma unroll
      for (int kx = 0; kx < 3; kx++) {
        int ix = ox * 2 + kx;
        xv[ci * 9 + ky * 3 + kx] = (iy < 32 && ix < 32) ? xs[ci * 1024 + iy * 32 + ix] : 0.f;
      }
    }
  const float* bn = b1 + n * 64;
  f16 ov[64];
#pragma unroll
  for (int co = 0; co < 64; co++) {
    const float* wp = &wsh[co * 27];
    float acc = bn[co];
#pragma unroll
    for (int q = 0; q < 27; q++) acc = fmaf(xv[q], wp[q], acc);
    ov[co] = (f16)fmaxf(acc, 0.f);
  }
  f16* ob = h1T + (((long)(n * 256 + b) * 17 + oy) * 17 + ox) * 64;
#pragma unroll
  for (int i = 0; i < 64; i += 8) *(f16x8*)&ob[i] = *(f16x8*)&ov[i];
  // zero guard ring: row 16 (17 cells) + col 16 (16 cells)
  if (t < 33) {
    int gy = (t < 17) ? 16 : (t - 17);
    int gx = (t < 17) ? t : 16;
    f16* gp = h1T + (((long)(n * 256 + b) * 17 + gy) * 17 + gx) * 64;
    f16x8 zz = {};
#pragma unroll
    for (int i = 0; i < 64; i += 8) *(f16x8*)&gp[i] = zz;
  }
}

// ---------------- conv2 MFMA + fused relu/bias/pool: out pooled16[e,b,128co] (scaled 1/64)
__global__ __launch_bounds__(256) void conv2_mfma(
    const f16* __restrict__ w2p, const float* __restrict__ b2,
    const f16* __restrict__ h1T, f16* __restrict__ pooled16)
{
  __shared__ __align__(16) f16 Asub[128 * 64]; // [co][ci] rows of 128B
  __shared__ __align__(16) f16 Bsub[64 * 64];  // [sp][ci]
  __shared__ float red[2][128];
  int b = blockIdx.x, e = blockIdx.y;
  int t = threadIdx.x, w = t >> 6, l = t & 63;
  int waveR = w >> 1, waveC = w & 1;
  f32x4 acc[4][2];
#pragma unroll
  for (int i = 0; i < 4; i++)
#pragma unroll
    for (int j = 0; j < 2; j++) acc[i][j] = (f32x4){0.f, 0.f, 0.f, 0.f};
  const f16* wbase = w2p + (long)e * 128 * 576;
  const f16* hbase = h1T + ((long)e * 256 + b) * 18496;
  for (int tap = 0; tap < 9; tap++) {
    int ky = tap / 3, kx = tap - ky * 3;
    __syncthreads(); // prev-tap fragment reads done before LDS overwrite
    // A: 16 chunks of 8 co-rows; wave w does 4
#pragma unroll
    for (int c = 0; c < 4; c++) {
      int ch = w * 4 + c;
      int co = ch * 8 + (l >> 3);
      int g = (l & 7) ^ (co & 7);
      const f16* src = wbase + ((long)co * 9 + tap) * 64 + g * 8;
      GLOAD_LDS16(src, &Asub[ch * 512]);
    }
    // B: 8 chunks of 8 sp-rows; wave w does 2
#pragma unroll
    for (int c = 0; c < 2; c++) {
      int ch = w * 2 + c;
      int sp = ch * 8 + (l >> 3);
      int g = (l & 7) ^ (sp & 7);
      int iy = (sp >> 3) * 2 + ky, ix = (sp & 7) * 2 + kx;
      const f16* src = hbase + ((long)iy * 17 + ix) * 64 + g * 8;
      GLOAD_LDS16(src, &Bsub[ch * 512]);
    }
    asm volatile("s_waitcnt vmcnt(0)" ::: "memory");
    __syncthreads();
#pragma unroll
    for (int kk = 0; kk < 2; kk++) {
      f16x8 af[4], bf[2];
#pragma unroll
      for (int i = 0; i < 4; i++) {
        int row = waveR * 64 + i * 16 + (l & 15);
        int blk = (kk * 4 + (l >> 4)) ^ (row & 7);
        af[i] = *(const f16x8*)&Asub[row * 64 + blk * 8];
      }
#pragma unroll
      for (int j = 0; j < 2; j++) {
        int col = waveC * 32 + j * 16 + (l & 15);
        int blk = (kk * 4 + (l >> 4)) ^ (col & 7);
        bf[j] = *(const f16x8*)&Bsub[col * 64 + blk * 8];
      }
#pragma unroll
      for (int i = 0; i < 4; i++)
#pragma unroll
        for (int j = 0; j < 2; j++)
          acc[i][j] = __builtin_amdgcn_mfma_f32_16x16x32_f16(af[i], bf[j], acc[i][j], 0, 0, 0);
    }
  }
  // epilogue: relu(acc + bias) summed over sp (cols), then /64
  const float* bn = b2 + e * 128;
#pragma unroll
  for (int i = 0; i < 4; i++) {
#pragma unroll
    for (int reg = 0; reg < 4; reg++) {
      int row = waveR * 64 + i * 16 + ((l >> 4) << 2) + reg;
      float bi = bn[row];
      float s = 0.f;
#pragma unroll
      for (int j = 0; j < 2; j++) s += fmaxf(acc[i][j][reg] + bi, 0.f);
      s += __shfl_xor(s, 1); s += __shfl_xor(s, 2);
      s += __shfl_xor(s, 4); s += __shfl_xor(s, 8);
      if ((l & 15) == 0) red[waveC][row] = s;
    }
  }
  __syncthreads();
  if (t < 128) {
    float v = (red[0][t] + red[1][t]) * (1.f / 64.f);
    pooled16[((long)e * 256 + b) * 128 + t] = (f16)v;
  }
}

// ---------------- generic segmented f16-MFMA GEMM: 128x64 tile, 4 waves, BK=64
struct SegsM {
  const f16* BT[4];       // [z][cols][K] f16
  const float* bias[4];
  long sBT[4];
  long sBias[4];
  int act[4]; // 0 none, 1 relu, 2 sigmoid, 3 tanh
};

__global__ __launch_bounds__(256) void gemmf16_kernel(
    const f16* __restrict__ A, long sA, int lda, SegsM segs, int K,
    float* __restrict__ C32, long sC32, int ldc32,
    f16* __restrict__ C16, f16* __restrict__ C16b, long sC16, int ldc16,
    float* __restrict__ aux32, f16* __restrict__ aux16, long sAux, int ldAux)
{
  __shared__ __align__(16) f16 Asub[128 * 64];
  __shared__ __align__(16) f16 Bsub[64 * 64];
  int z = blockIdx.z;
  int rowBase = blockIdx.y * 128;
  int vcBase = blockIdx.x * 64;
  int seg = vcBase >> 9;
  int lcBase = vcBase & 511;
  const f16* An = A + (long)z * sA;
  const f16* BTn = segs.BT[seg] + (long)z * segs.sBT[seg];
  const float* biasN = segs.bias[seg] ? segs.bias[seg] + (long)z * segs.sBias[seg] : nullptr;
  int act = segs.act[seg];
  int t = threadIdx.x, w = t >> 6, l = t & 63;
  int waveR = w >> 1, waveC = w & 1;
  f32x4 acc[4][2];
#pragma unroll
  for (int i = 0; i < 4; i++)
#pragma unroll
    for (int j = 0; j < 2; j++) acc[i][j] = (f32x4){0.f, 0.f, 0.f, 0.f};
  int nk = K >> 6;
  for (int kt = 0; kt < nk; kt++) {
    int k0 = kt << 6;
    __syncthreads();
#pragma unroll
    for (int c = 0; c < 4; c++) {
      int ch = w * 4 + c;
      int row = ch * 8 + (l >> 3);
      int g = (l & 7) ^ (row & 7);
      const f16* src = An + (long)(rowBase + row) * lda + k0 + g * 8;
      GLOAD_LDS16(src, &Asub[ch * 512]);
    }
#pragma unroll
    for (int c = 0; c < 2; c++) {
      int ch = w * 2 + c;
      int col = ch * 8 + (l >> 3);
      int g = (l & 7) ^ (col & 7);
      const f16* src = BTn + (long)(lcBase + col) * K + k0 + g * 8;
      GLOAD_LDS16(src, &Bsub[ch * 512]);
    }
    asm volatile("s_waitcnt vmcnt(0)" ::: "memory");
    __syncthreads();
#pragma unroll
    for (int kk = 0; kk < 2; kk++) {
      f16x8 af[4], bf[2];
#pragma unroll
      for (int i = 0; i < 4; i++) {
        int row = waveR * 64 + i * 16 + (l & 15);
        int blk = (kk * 4 + (l >> 4)) ^ (row & 7);
        af[i] = *(const f16x8*)&Asub[row * 64 + blk * 8];
      }
#pragma unroll
      for (int j = 0; j < 2; j++) {
        int col = waveC * 32 + j * 16 + (l & 15);
        int blk = (kk * 4 + (l >> 4)) ^ (col & 7);
        bf[j] = *(const f16x8*)&Bsub[col * 64 + blk * 8];
      }
#pragma unroll
      for (int i = 0; i < 4; i++)
#pragma unroll
        for (int j = 0; j < 2; j++)
          acc[i][j] = __builtin_amdgcn_mfma_f32_16x16x32_f16(af[i], bf[j], acc[i][j], 0, 0, 0);
    }
  }
  int lcW = lcBase + waveC * 32;
#pragma unroll
  for (int i = 0; i < 4; i++) {
    int rb = rowBase + waveR * 64 + i * 16 + ((l >> 4) << 2);
#pragma unroll
    for (int j = 0; j < 2; j++) {
      int lc = lcW + j * 16 + (l & 15);
      int vc = (seg << 9) + lc;
      float bv = biasN ? biasN[lc] : 0.f;
#pragma unroll
      for (int reg = 0; reg < 4; reg++) {
        float v = acc[i][j][reg] + bv;
        if (act == 1) v = fmaxf(v, 0.f);
        else if (act == 2) v = 1.f / (1.f + __expf(-v));
        else if (act == 3) v = tanhf(v);
        long rr = rb + reg;
        if (C32) C32[(long)z * sC32 + rr * ldc32 + vc] = v;
        if (C16) C16[(long)z * sC16 + rr * ldc16 + vc] = (f16)v;
        if (C16b) C16b[(long)z * sC16 + rr * ldc16 + vc] = (f16)v;
        if (aux32) {
          long ai = (long)z * sAux + rr * ldAux + vc;
          float nv = aux32[ai] + v;
          aux32[ai] = nv;
          aux16[ai] = (f16)nv;
        }
      }
    }
  }
}

// ---------------- GRU controller + send/recv/ab gates (fp32)
__global__ __launch_bounds__(64) void gru_kernel(
    const float* __restrict__ qkv, const float* __restrict__ wh, const float* __restrict__ bh,
    float* __restrict__ cs, const float* __restrict__ sw, const float* __restrict__ sb,
    const float* __restrict__ rw, const float* __restrict__ rb,
    const float* __restrict__ aw, const float* __restrict__ abb,
    float* __restrict__ send, float* __restrict__ recv, float* __restrict__ ab)
{
  int b = blockIdx.x, n = blockIdx.y, hc = threadIdx.x;
  __shared__ float csh[64];
  long nb = (long)n * 256 + b;
  float c0 = cs[nb * 64 + hc];
  csh[hc] = c0;
  __syncthreads();
  const float* whn = wh + (long)n * 64 * 192;
  float g0 = bh[n * 192 + hc], g1 = bh[n * 192 + 64 + hc], g2 = bh[n * 192 + 128 + hc];
  for (int k = 0; k < 64; k++) {
    float cv = csh[k];
    g0 = fmaf(cv, whn[k * 192 + hc], g0);
    g1 = fmaf(cv, whn[k * 192 + 64 + hc], g1);
    g2 = fmaf(cv, whn[k * 192 + 128 + hc], g2);
  }
  const float* gi = qkv + nb * 1728 + 1536;
  float iz = gi[hc], ir = gi[64 + hc], inn = gi[128 + hc];
  float zg = 1.f / (1.f + __expf(-(iz + g0)));
  float rg = 1.f / (1.f + __expf(-(ir + g1)));
  float ng = tanhf(inn + rg * g2);
  float cn = (1.f - zg) * ng + zg * c0;
  cs[nb * 64 + hc] = cn;
  float ps = cn * sw[n * 64 + hc];
  float pr = cn * rw[n * 64 + hc];
#pragma unroll
  for (int o = 32; o; o >>= 1) { ps += __shfl_xor(ps, o); pr += __shfl_xor(pr, o); }
  if (hc == 0) {
    send[n * 256 + b] = 1.f / (1.f + __expf(-(ps + sb[n])));
    recv[n * 256 + b] = 1.f / (1.f + __expf(-(pr + rb[n])));
  }
#pragma unroll
  for (int kk = 0; kk < 8; kk++) {
    float pa = cn * aw[(n * 64 + hc) * 8 + kk];
#pragma unroll
    for (int o = 32; o; o >>= 1) pa += __shfl_xor(pa, o);
    if (hc == 0) ab[nb * 8 + kk] = pa + abb[n * 8 + kk];
  }
}

// ---------------- 8-node graph attention (fp32 compute, f16 msg out)
__global__ __launch_bounds__(256) void attn_kernel(
    const float* __restrict__ qkv, const float* __restrict__ edge,
    const float* __restrict__ send, const float* __restrict__ recv,
    const float* __restrict__ ab, f16* __restrict__ msg16)
{
  int b = blockIdx.x, t = threadIdx.x;
  __shared__ float qs[8 * 520], ks[8 * 520], vs[8 * 520];
  __shared__ float sc[512];
  __shared__ float se[8], re[8], edg[64], abl[64];
  for (int i = t; i < 4096; i += 256) {
    int nn = i >> 9, c = i & 511, h = c >> 6, d = c & 63;
    long base = ((long)nn * 256 + b) * 1728 + c;
    int la = nn * 520 + h * 65 + d;
    qs[la] = qkv[base];
    ks[la] = qkv[base + 512];
    vs[la] = qkv[base + 1024];
  }
  if (t < 8) { se[t] = send[t * 256 + b]; re[t] = recv[t * 256 + b]; }
  if (t >= 64 && t < 128) edg[t - 64] = edge[t - 64];
  if (t >= 128 && t < 192) { int q = t - 128; abl[q] = ab[((long)(q >> 3) * 256 + b) * 8 + (q & 7)]; }
  __syncthreads();
  for (int idx = t; idx < 512; idx += 256) {
    int i = idx >> 6, j = (idx >> 3) & 7, h = idx & 7;
    const float* qp = &qs[i * 520 + h * 65];
    const float* kp = &ks[j * 520 + h * 65];
    float s = 0.f;
#pragma unroll
    for (int d = 0; d < 64; d++) s = fmaf(qp[d], kp[d], s);
    sc[idx] = s * 0.125f + edg[i * 8 + j] + abl[i * 8 + h];
  }
  __syncthreads();
  if (t < 64) {
    int i = t >> 3, h = t & 7;
    float mx = -1e30f;
#pragma unroll
    for (int j = 0; j < 8; j++) mx = fmaxf(mx, sc[(i << 6) + (j << 3) + h]);
    float e[8], sm = 0.f;
#pragma unroll
    for (int j = 0; j < 8; j++) { e[j] = __expf(sc[(i << 6) + (j << 3) + h] - mx); sm += e[j]; }
    float inv = re[i] / sm;
#pragma unroll
    for (int j = 0; j < 8; j++) sc[(i << 6) + (j << 3) + h] = e[j] * inv * se[j];
  }
  __syncthreads();
  for (int idx = t; idx < 4096; idx += 256) {
    int i = idx >> 9, c = idx & 511, h = c >> 6, d = c & 63;
    float s = 0.f;
#pragma unroll
    for (int j = 0; j < 8; j++) s = fmaf(sc[(i << 6) + (j << 3) + h], vs[j * 520 + h * 65 + d], s);
    msg16[((long)i * 256 + b) * 512 + c] = (f16)s;
  }
}

// ---------------- h = (1-g)*h + g*cand; h kept fp32 + f16 mirror in cat16
__global__ __launch_bounds__(256) void hupdate_kernel(
    float* __restrict__ h32, f16* __restrict__ cat16, const float* __restrict__ gc)
{
  long idx = (long)blockIdx.x * 256 + threadIdx.x; // 1,048,576
  long nb = idx >> 9; int m = (int)(idx & 511);
  float g = gc[nb * 1024 + m];
  float cd = gc[nb * 1024 + 512 + m];
  float h = h32[idx];
  float nh = (1.f - g) * h + g * cd;
  h32[idx] = nh;
  cat16[nb * 1536 + m] = (f16)nh;
}

// ---------------- classifier (fp32): h32[8,256,512] x wcls[512,100] + bias -> d_out
__global__ __launch_bounds__(256) void cls_kernel(
    const float* __restrict__ h32, const float* __restrict__ wcls,
    const float* __restrict__ bcls, float* __restrict__ out)
{
  __shared__ float As[2][512];
  int n = blockIdx.x >> 7, r0 = (blockIdx.x & 127) * 2;
  int t = threadIdx.x;
  for (int i = t; i < 1024; i += 256)
    As[i >> 9][i & 511] = h32[((long)(n * 256 + r0 + (i >> 9))) * 512 + (i & 511)];
  __syncthreads();
  int r = r0 + (t >> 7), c = t & 127;
  if (c < 100) {
    const float* wp = wcls + (long)n * 512 * 100 + c;
    const float* arow = As[t >> 7];
    float acc = bcls[n * 100 + c];
#pragma unroll 4
    for (int k = 0; k < 512; k++) acc = fmaf(arow[k], wp[k * 100], acc);
    out[((long)(n * 256 + r)) * 100 + c] = acc;
  }
}

extern "C" void kernel_launch(void* const* d_in, const int* in_sizes, int n_in,
                              void* d_out, int out_size, void* d_ws, size_t ws_size,
                              hipStream_t stream)
{
  (void)in_sizes; (void)n_in; (void)out_size;
  const float* x        = (const float*)d_in[0];
  const float* conv1_w  = (const float*)d_in[1];
  const float* conv1_b  = (const float*)d_in[2];
  const float* conv2_w  = (const float*)d_in[3];
  const float* conv2_b  = (const float*)d_in[4];
  const float* feat_w   = (const float*)d_in[5];
  const float* feat_b   = (const float*)d_in[6];
  const float* ctrl_wi  = (const float*)d_in[7];
  const float* ctrl_wh  = (const float*)d_in[8];
  const float* ctrl_bi  = (const float*)d_in[9];
  const float* ctrl_bh  = (const float*)d_in[10];
  const float* send_w   = (const float*)d_in[11];
  const float* send_b   = (const float*)d_in[12];
  const float* recv_w   = (const float*)d_in[13];
  const float* recv_b   = (const float*)d_in[14];
  const float* abias_w  = (const float*)d_in[15];
  const float* abias_b  = (const float*)d_in[16];
  const float* wq       = (const float*)d_in[17];
  const float* wk       = (const float*)d_in[18];
  const float* wv       = (const float*)d_in[19];
  const float* wo       = (const float*)d_in[20];
  const float* bo       = (const float*)d_in[21];
  const float* edge     = (const float*)d_in[22];
  const float* wr       = (const float*)d_in[23];
  const float* br       = (const float*)d_in[24];
  const float* wg       = (const float*)d_in[25];
  const float* bg       = (const float*)d_in[26];
  const float* wc       = (const float*)d_in[27];
  const float* bc       = (const float*)d_in[28];
  const float* wcls     = (const float*)d_in[29];
  const float* bcls     = (const float*)d_in[30];

  // ---- workspace layout
  float* f32b = (float*)d_ws;
  float* h32    = f32b;              // 1,048,576
  float* qkvb   = f32b + 1048576;    // 3,538,944
  float* gc     = f32b + 4587520;    // 2,097,152
  float* msum32 = f32b + 6684672;    // 1,048,576
  float* cs     = f32b + 7733248;    // 131,072
  float* sendb  = f32b + 7864320;    // 2,048
  float* recvb  = f32b + 7866368;    // 2,048
  float* abb    = f32b + 7868416;    // 16,384
  // f32 total: 7,884,800 floats = 31,539,200 bytes (16B aligned)
  f16* hb = (f16*)(f32b + 7884800);
  f16* h1T      = hb;                // 8*256*17*17*64 = 37,879,808
  f16* pooled16 = hb + 37879808;     // 262,144
  f16* cat16    = hb + 38141952;     // 3,145,728  [h|feats|readout]
  f16* msg16    = hb + 41287680;     // 1,048,576
  f16* msum16   = hb + 42336256;     // 1,048,576
  f16* wqT      = hb + 43384832;     // 2,097,152
  f16* wkT      = hb + 45481984;     // 2,097,152
  f16* wvT      = hb + 47579136;     // 2,097,152
  f16* wiT      = hb + 49676288;     // 786,432
  f16* featwT   = hb + 50462720;     // 524,288
  f16* woT      = hb + 50987008;     // 2,097,152
  f16* wrT      = hb + 53084160;     // 2,097,152
  f16* wgT      = hb + 55181312;     // 6,291,456
  f16* wcT      = hb + 61472768;     // 6,291,456
  f16* c2wp     = hb + 67764224;     // 589,824
  // f16 total: 68,354,048 halves; grand total ~168.2 MB
  if (ws_size < 31539200ull + 68354048ull * 2ull) return;

  hipMemsetAsync(cs, 0, 131072 * 4, stream);
  hipMemsetAsync(msum32, 0, 1048576 * 4, stream);

  // ---- one-time weight conversions (transposed to [cols][K] f16)
  twconv_kernel<<<dim3(16, 16, 8), 256, 0, stream>>>(wq, wqT, 512, 512, 1.f);
  twconv_kernel<<<dim3(16, 16, 8), 256, 0, stream>>>(wk, wkT, 512, 512, 1.f);
  twconv_kernel<<<dim3(16, 16, 8), 256, 0, stream>>>(wv, wvT, 512, 512, 1.f);
  twconv_kernel<<<dim3(6, 16, 8), 256, 0, stream>>>(ctrl_wi, wiT, 512, 192, 1.f);
  twconv_kernel<<<dim3(16, 4, 8), 256, 0, stream>>>(feat_w, featwT, 128, 512, 1.f);
  twconv_kernel<<<dim3(16, 16, 8), 256, 0, stream>>>(wo, woT, 512, 512, 1.f);
  twconv_kernel<<<dim3(16, 16, 8), 256, 0, stream>>>(wr, wrT, 512, 512, 0.125f); // fold /8
  twconv_kernel<<<dim3(16, 48, 8), 256, 0, stream>>>(wg, wgT, 1536, 512, 1.f);
  twconv_kernel<<<dim3(16, 48, 8), 256, 0, stream>>>(wc, wcT, 1536, 512, 1.f);
  c2wconv_kernel<<<2304, 256, 0, stream>>>(conv2_w, c2wp);

  // ---- feature extraction
  conv1_kernel<<<dim3(256, 8), 256, 0, stream>>>(x, conv1_w, conv1_b, h1T);
  conv2_mfma<<<dim3(256, 8), 256, 0, stream>>>(c2wp, conv2_b, h1T, pooled16);

  // feats = relu(pooled @ feat_w + b) -> cat16[512:1024], h-init -> cat16[0:512] + h32
  {
    SegsM s{};
    s.BT[0] = featwT; s.sBT[0] = 65536; s.bias[0] = feat_b; s.sBias[0] = 512; s.act[0] = 1;
    gemmf16_kernel<<<dim3(8, 2, 8), 256, 0, stream>>>(
        pooled16, 32768L, 128, s, 128,
        h32, 131072L, 512,
        cat16 + 512, cat16, 393216L, 1536,
        nullptr, nullptr, 0L, 0);
  }

  for (int step = 0; step < 3; step++) {
    // q|k|v|gi = cat16[h] @ {wq,wk,wv,ctrl_wi}  (K=512 -> uses only h slice)
    {
      SegsM s{};
      s.BT[0] = wqT; s.BT[1] = wkT; s.BT[2] = wvT; s.BT[3] = wiT;
      s.sBT[0] = 262144; s.sBT[1] = 262144; s.sBT[2] = 262144; s.sBT[3] = 98304;
      s.bias[3] = ctrl_bi; s.sBias[3] = 192;
      gemmf16_kernel<<<dim3(27, 2, 8), 256, 0, stream>>>(
          cat16, 393216L, 1536, s, 512,
          qkvb, 442368L, 1728,
          nullptr, nullptr, 0L, 0,
          nullptr, nullptr, 0L, 0);
    }
    gru_kernel<<<dim3(256, 8), 64, 0, stream>>>(
        qkvb, ctrl_wh, ctrl_bh, cs, send_w, send_b, recv_w, recv_b,
        abias_w, abias_b, sendb, recvb, abb);
    attn_kernel<<<256, 256, 0, stream>>>(qkvb, edge, sendb, recvb, abb, msg16);
    // msum += msg @ wo + bo  (fp32 accum, f16 mirror)
    {
      SegsM s{};
      s.BT[0] = woT; s.sBT[0] = 262144; s.bias[0] = bo; s.sBias[0] = 512;
      gemmf16_kernel<<<dim3(8, 2, 8), 256, 0, stream>>>(
          msg16, 131072L, 512, s, 512,
          nullptr, 0L, 0,
          nullptr, nullptr, 0L, 0,
          msum32, msum16, 131072L, 512);
    }
    // readout = (msum/8) @ wr + br -> cat16[1024:1536]   (1/8 folded into wrT)
    {
      SegsM s{};
      s.BT[0] = wrT; s.sBT[0] = 262144; s.bias[0] = br; s.sBias[0] = 512;
      gemmf16_kernel<<<dim3(8, 2, 8), 256, 0, stream>>>(
          msum16, 131072L, 512, s, 512,
          nullptr, 0L, 0,
          cat16 + 1024, nullptr, 393216L, 1536,
          nullptr, nullptr, 0L, 0);
    }
    // g|cand = sigmoid/tanh(cat16 @ [wg|wc] + [bg|bc]) -> gc fp32
    {
      SegsM s{};
      s.BT[0] = wgT; s.BT[1] = wcT;
      s.sBT[0] = 786432; s.sBT[1] = 786432;
      s.bias[0] = bg; s.bias[1] = bc; s.sBias[0] = 512; s.sBias[1] = 512;
      s.act[0] = 2; s.act[1] = 3;
      gemmf16_kernel<<<dim3(16, 2, 8), 256, 0, stream>>>(
          cat16, 393216L, 1536, s, 1536,
          gc, 262144L, 1024,
          nullptr, nullptr, 0L, 0,
          nullptr, nullptr, 0L, 0);
    }
    hupdate_kernel<<<4096, 256, 0, stream>>>(h32, cat16, gc);
  }
  cls_kernel<<<1024, 256, 0, stream>>>(h32, wcls, bcls, (float*)d_out);
}

// Round 3
// 486.838 us; speedup vs baseline: 3.5449x; 1.0721x over previous
//
#include <hip/hip_runtime.h>
#include <hip/hip_bf16.h>

// DNBN system, f16-MFMA, round 3.
// N=8, B=256, M=512, C=512, NH=8, DH=64, S=8, HC=64, T=3, OUT=100.
// T(3) < S(8) -> FIFO never evicts -> buf.mean == msum/8.
// New this round: fused conv1+conv2+pool (h1 tile lives in LDS only);
// wo/wr GEMM pair collapsed via worT = (wo@wr)/8 precompute;
// 64x64-tile double-buffered GEMM; vectorized weight transposes.

typedef _Float16 f16;
typedef _Float16 f16x8 __attribute__((ext_vector_type(8)));
typedef float f32x4 __attribute__((ext_vector_type(4)));

#define GLOAD_LDS16(gsrc, ldst)                                                   \
  __builtin_amdgcn_global_load_lds(                                               \
      (const __attribute__((address_space(1))) void*)(gsrc),                      \
      (__attribute__((address_space(3))) void*)(ldst), 16, 0, 0)

// ---------------- transpose+convert: src [8][K][N] f32 -> dst [8][N][K] f16 (scaled)
// K,N multiples of 64.
__global__ __launch_bounds__(256) void tw64_kernel(
    const float* __restrict__ src, f16* __restrict__ dst, int K, int N, float scale)
{
  __shared__ float tile[64][65];
  int z = blockIdx.z;
  int n0 = blockIdx.x * 64, k0 = blockIdx.y * 64;
  const float* s = src + (long)z * K * N;
  f16* d = dst + (long)z * N * K;
  int t = threadIdx.x;
#pragma unroll
  for (int p = 0; p < 4; p++) {
    int idx = t + p * 256;
    int kk = idx >> 4, nq = (idx & 15) * 4;
    float4 v = *(const float4*)&s[(long)(k0 + kk) * N + n0 + nq];
    tile[kk][nq] = v.x; tile[kk][nq + 1] = v.y; tile[kk][nq + 2] = v.z; tile[kk][nq + 3] = v.w;
  }
  __syncthreads();
#pragma unroll
  for (int p = 0; p < 2; p++) {
    int idx = t + p * 256;
    int nn = idx >> 3, kc = (idx & 7) * 8;
    f16 o[8];
#pragma unroll
    for (int i = 0; i < 8; i++) o[i] = (f16)(tile[kc + i][nn] * scale);
    *(f16x8*)&d[(long)(n0 + nn) * K + k0 + kc] = *(const f16x8*)o;
  }
}

// ---------------- straight f32 -> f16 convert (wo)
__global__ __launch_bounds__(256) void cconv_kernel(const float* __restrict__ s, f16* __restrict__ d)
{
  long i = ((long)blockIdx.x * 256 + threadIdx.x) * 8;
  float4 a = *(const float4*)&s[i];
  float4 b = *(const float4*)&s[i + 4];
  f16 o[8] = {(f16)a.x, (f16)a.y, (f16)a.z, (f16)a.w, (f16)b.x, (f16)b.y, (f16)b.z, (f16)b.w};
  *(f16x8*)&d[i] = *(const f16x8*)o;
}

// ---------------- conv2 weight permute: [8][128co][64ci][3][3] -> [8][128co][9tap][64ci] f16
__global__ __launch_bounds__(256) void c2wconv_kernel(const float* __restrict__ src, f16* __restrict__ dst)
{
  long i = (long)blockIdx.x * 256 + threadIdx.x; // 589824
  int ci = i & 63; long r = i >> 6; int tap = r % 9; r /= 9; int co = r & 127; int n = (int)(r >> 7);
  dst[i] = (f16)src[(((long)(n * 128 + co) * 64 + ci) * 9) + tap];
}

// ---------------- bor[n][m] = (bo @ wr)[m] / 8
__global__ __launch_bounds__(256) void bor_kernel(
    const float* __restrict__ bo, const float* __restrict__ wr, float* __restrict__ bor)
{
  int n = blockIdx.y, m = blockIdx.x * 256 + threadIdx.x; // grid (2,8)
  const float* w = wr + (long)n * 512 * 512;
  const float* b = bo + n * 512;
  float s = 0.f;
  for (int c = 0; c < 512; c++) s = fmaf(b[c], w[(long)c * 512 + m], s);
  bor[n * 512 + m] = s * 0.125f;
}

// ---------------- fused conv1+conv2+pool: one block per (b,e); h1 tile in LDS only.
// x[256,3,32,32] -conv1,s2,relu-> h1 16x16x64 (LDS f16, swizzled, guard ring)
// -conv2 MFMA (9 taps, A dbuf)-> relu+bias+mean -> pooled16[e,b,128] (/64)
__global__ __launch_bounds__(256) void convfused_kernel(
    const float* __restrict__ x, const float* __restrict__ w1, const float* __restrict__ b1,
    const f16* __restrict__ w2p, const float* __restrict__ b2, f16* __restrict__ pooled16)
{
  __shared__ __align__(16) char lds[70784];
  f16* h1s = (f16*)lds;              // 36992 B: [289 pixels][64ci], chunk g at slot g^f(p)
  f16* Asub = (f16*)(lds + 36992);   // 32768 B: 2 x [128co][64ci]
  float* red = (float*)(lds + 69760);
  float* xs = (float*)(lds + 36992); // aliases Asub (dead after conv1)

  int b = blockIdx.x, e = blockIdx.y;
  int t = threadIdx.x, w = t >> 6, l = t & 63;
  int waveR = w >> 1, waveC = w & 1;

  const float* xb = x + (long)b * 3072;
  for (int i = t; i < 768; i += 256) ((float4*)xs)[i] = ((const float4*)xb)[i];
  __syncthreads();

  // conv1 for pixel (oy,ox)
  int oy = t >> 4, ox = t & 15;
  float xv[27];
#pragma unroll
  for (int ci = 0; ci < 3; ci++)
#pragma unroll
    for (int ky = 0; ky < 3; ky++) {
      int iy = oy * 2 + ky;
#pragma unroll
      for (int kx = 0; kx < 3; kx++) {
        int ix = ox * 2 + kx;
        xv[ci * 9 + ky * 3 + kx] = (iy < 32 && ix < 32) ? xs[ci * 1024 + iy * 32 + ix] : 0.f;
      }
    }
  const float* wn = w1 + (long)e * 1728;  // wave-uniform -> scalar loads
  const float* bn1 = b1 + e * 64;
  f16 ov[64];
#pragma unroll
  for (int co = 0; co < 64; co++) {
    float acc = bn1[co];
#pragma unroll
    for (int q = 0; q < 27; q++) acc = fmaf(xv[q], wn[co * 27 + q], acc);
    ov[co] = (f16)fmaxf(acc, 0.f);
  }
  __syncthreads(); // xs reads done -> Asub region reusable
  {
    int p = oy * 17 + ox;
    int fs = ((ox >> 1) + oy) & 7;
#pragma unroll
    for (int g = 0; g < 8; g++)
      *(f16x8*)&h1s[p * 64 + ((g ^ fs) * 8)] = *(const f16x8*)&ov[g * 8];
  }
  if (t < 33) { // zero guard ring (row 16 + col 16)
    int gy = (t < 17) ? 16 : (t - 17);
    int gx = (t < 17) ? t : 16;
    int p = gy * 17 + gx;
    f16x8 zz = {};
#pragma unroll
    for (int g = 0; g < 8; g++) *(f16x8*)&h1s[p * 64 + g * 8] = zz;
  }

  const f16* wbase = w2p + (long)e * 73728;
  auto stageA = [&](int buf, int tap) {
#pragma unroll
    for (int c = 0; c < 4; c++) {
      int ch = w * 4 + c;
      int co = ch * 8 + (l >> 3);
      int g = (l & 7) ^ (co & 7);
      GLOAD_LDS16(wbase + ((long)co * 9 + tap) * 64 + g * 8, &Asub[buf * 8192 + ch * 512]);
    }
  };
  stageA(0, 0);
  asm volatile("s_waitcnt vmcnt(0)" ::: "memory");
  __syncthreads(); // h1s writes + stage(0) complete

  f32x4 acc[4][2];
#pragma unroll
  for (int i = 0; i < 4; i++) {
    acc[i][0] = (f32x4){0.f, 0.f, 0.f, 0.f};
    acc[i][1] = (f32x4){0.f, 0.f, 0.f, 0.f};
  }
  int cur = 0;
  for (int tap = 0; tap < 9; tap++) {
    if (tap < 8) stageA(cur ^ 1, tap + 1);
    int ky = tap / 3, kx = tap - ky * 3;
#pragma unroll
    for (int kk = 0; kk < 2; kk++) {
      f16x8 af[4], bf[2];
#pragma unroll
      for (int i = 0; i < 4; i++) {
        int row = waveR * 64 + i * 16 + (l & 15);
        int blk = (kk * 4 + (l >> 4)) ^ (row & 7);
        af[i] = *(const f16x8*)&Asub[cur * 8192 + row * 64 + blk * 8];
      }
#pragma unroll
      for (int j = 0; j < 2; j++) {
        int sp = waveC * 32 + j * 16 + (l & 15);
        int iy = (sp >> 3) * 2 + ky, ix = (sp & 7) * 2 + kx;
        int fs = ((ix >> 1) + iy) & 7;
        int blk = (kk * 4 + (l >> 4)) ^ fs;
        bf[j] = *(const f16x8*)&h1s[(iy * 17 + ix) * 64 + blk * 8];
      }
#pragma unroll
      for (int i = 0; i < 4; i++)
#pragma unroll
        for (int j = 0; j < 2; j++)
          acc[i][j] = __builtin_amdgcn_mfma_f32_16x16x32_f16(af[i], bf[j], acc[i][j], 0, 0, 0);
    }
    if (tap < 8) {
      asm volatile("s_waitcnt vmcnt(0)" ::: "memory");
      __syncthreads();
      cur ^= 1;
    }
  }
  // epilogue: relu(acc+bias) summed over 64 spatial cols, /64
  const float* bn2 = b2 + e * 128;
#pragma unroll
  for (int i = 0; i < 4; i++) {
#pragma unroll
    for (int reg = 0; reg < 4; reg++) {
      int row = waveR * 64 + i * 16 + ((l >> 4) << 2) + reg;
      float bi = bn2[row];
      float s = fmaxf(acc[i][0][reg] + bi, 0.f) + fmaxf(acc[i][1][reg] + bi, 0.f);
      s += __shfl_xor(s, 1); s += __shfl_xor(s, 2);
      s += __shfl_xor(s, 4); s += __shfl_xor(s, 8);
      if ((l & 15) == 0) red[waveC * 128 + row] = s;
    }
  }
  __syncthreads();
  if (t < 128) {
    float v = (red[t] + red[128 + t]) * (1.f / 64.f);
    pooled16[((long)e * 256 + b) * 128 + t] = (f16)v;
  }
}

// ---------------- segmented f16-MFMA GEMM: 64x64 tile, 4 waves, BK=64, 2-phase dbuf
struct SegsM {
  const f16* BT[4];        // [z][cols][K]
  const float* bias[4];
  const float* bias2[4];   // optional second bias, scaled by b2scale
  long sBT[4];
  long sBias[4];
  long sBias2[4];
  int act[4];              // 0 none, 1 relu, 2 sigmoid, 3 tanh
};

__global__ __launch_bounds__(256) void gemmf16_kernel(
    const f16* __restrict__ A, long sA, int lda, SegsM segs, int K, float b2scale,
    float* __restrict__ C32, long sC32, int ldc32,
    f16* __restrict__ C16, f16* __restrict__ C16b, long sC16, int ldc16)
{
  __shared__ __align__(16) f16 Asub[2][64 * 64];
  __shared__ __align__(16) f16 Bsub[2][64 * 64];
  int z = blockIdx.z;
  int rowBase = blockIdx.y * 64;
  int vcBase = blockIdx.x * 64;
  int seg = vcBase >> 9;
  int lcBase = vcBase & 511;
  const f16* An = A + (long)z * sA + (long)rowBase * lda;
  const f16* BTn = segs.BT[seg] + (long)z * segs.sBT[seg] + (long)lcBase * K;
  const float* biasN = segs.bias[seg] ? segs.bias[seg] + (long)z * segs.sBias[seg] : nullptr;
  const float* bias2N = segs.bias2[seg] ? segs.bias2[seg] + (long)z * segs.sBias2[seg] : nullptr;
  int act = segs.act[seg];
  int t = threadIdx.x, w = t >> 6, l = t & 63;
  int waveR = w >> 1, waveC = w & 1;
  f32x4 acc[2][2];
#pragma unroll
  for (int i = 0; i < 2; i++) {
    acc[i][0] = (f32x4){0.f, 0.f, 0.f, 0.f};
    acc[i][1] = (f32x4){0.f, 0.f, 0.f, 0.f};
  }
  auto stage = [&](int buf, int kt) {
    int k0 = kt << 6;
#pragma unroll
    for (int c = 0; c < 2; c++) {
      int ch = w * 2 + c;
      int row = ch * 8 + (l >> 3);
      int g = (l & 7) ^ (row & 7);
      GLOAD_LDS16(An + (long)row * lda + k0 + g * 8, &Asub[buf][ch * 512]);
    }
#pragma unroll
    for (int c = 0; c < 2; c++) {
      int ch = w * 2 + c;
      int col = ch * 8 + (l >> 3);
      int g = (l & 7) ^ (col & 7);
      GLOAD_LDS16(BTn + (long)col * K + k0 + g * 8, &Bsub[buf][ch * 512]);
    }
  };
  int nk = K >> 6;
  stage(0, 0);
  asm volatile("s_waitcnt vmcnt(0)" ::: "memory");
  __syncthreads();
  int cur = 0;
  for (int kt = 0; kt < nk; kt++) {
    if (kt + 1 < nk) stage(cur ^ 1, kt + 1);
#pragma unroll
    for (int kk = 0; kk < 2; kk++) {
      f16x8 af[2], bf[2];
#pragma unroll
      for (int i = 0; i < 2; i++) {
        int row = waveR * 32 + i * 16 + (l & 15);
        int blk = (kk * 4 + (l >> 4)) ^ (row & 7);
        af[i] = *(const f16x8*)&Asub[cur][row * 64 + blk * 8];
      }
#pragma unroll
      for (int j = 0; j < 2; j++) {
        int col = waveC * 32 + j * 16 + (l & 15);
        int blk = (kk * 4 + (l >> 4)) ^ (col & 7);
        bf[j] = *(const f16x8*)&Bsub[cur][col * 64 + blk * 8];
      }
#pragma unroll
      for (int i = 0; i < 2; i++)
#pragma unroll
        for (int j = 0; j < 2; j++)
          acc[i][j] = __builtin_amdgcn_mfma_f32_16x16x32_f16(af[i], bf[j], acc[i][j], 0, 0, 0);
    }
    if (kt + 1 < nk) {
      asm volatile("s_waitcnt vmcnt(0)" ::: "memory");
      __syncthreads();
      cur ^= 1;
    }
  }
  int lcW = lcBase + waveC * 32;
#pragma unroll
  for (int i = 0; i < 2; i++) {
    int rb = rowBase + waveR * 32 + i * 16 + ((l >> 4) << 2);
#pragma unroll
    for (int j = 0; j < 2; j++) {
      int lc = lcW + j * 16 + (l & 15);
      int vc = (seg << 9) + lc;
      float bv = biasN ? biasN[lc] : 0.f;
      if (bias2N) bv += b2scale * bias2N[lc];
#pragma unroll
      for (int reg = 0; reg < 4; reg++) {
        float v = acc[i][j][reg] + bv;
        if (act == 1) v = fmaxf(v, 0.f);
        else if (act == 2) v = 1.f / (1.f + __expf(-v));
        else if (act == 3) v = tanhf(v);
        long rr = rb + reg;
        if (C32) C32[(long)z * sC32 + rr * ldc32 + vc] = v;
        if (C16) C16[(long)z * sC16 + rr * ldc16 + vc] = (f16)v;
        if (C16b) C16b[(long)z * sC16 + rr * ldc16 + vc] = (f16)v;
      }
    }
  }
}

// ---------------- GRU controller + send/recv/ab gates (fp32)
__global__ __launch_bounds__(64) void gru_kernel(
    const float* __restrict__ qkv, const float* __restrict__ wh, const float* __restrict__ bh,
    float* __restrict__ cs, const float* __restrict__ sw, const float* __restrict__ sb,
    const float* __restrict__ rw, const float* __restrict__ rb,
    const float* __restrict__ aw, const float* __restrict__ abb,
    float* __restrict__ send, float* __restrict__ recv, float* __restrict__ ab)
{
  int b = blockIdx.x, n = blockIdx.y, hc = threadIdx.x;
  __shared__ float csh[64];
  long nb = (long)n * 256 + b;
  float c0 = cs[nb * 64 + hc];
  csh[hc] = c0;
  __syncthreads();
  const float* whn = wh + (long)n * 64 * 192;
  float g0 = bh[n * 192 + hc], g1 = bh[n * 192 + 64 + hc], g2 = bh[n * 192 + 128 + hc];
  for (int k = 0; k < 64; k++) {
    float cv = csh[k];
    g0 = fmaf(cv, whn[k * 192 + hc], g0);
    g1 = fmaf(cv, whn[k * 192 + 64 + hc], g1);
    g2 = fmaf(cv, whn[k * 192 + 128 + hc], g2);
  }
  const float* gi = qkv + nb * 1728 + 1536;
  float iz = gi[hc], ir = gi[64 + hc], inn = gi[128 + hc];
  float zg = 1.f / (1.f + __expf(-(iz + g0)));
  float rg = 1.f / (1.f + __expf(-(ir + g1)));
  float ng = tanhf(inn + rg * g2);
  float cn = (1.f - zg) * ng + zg * c0;
  cs[nb * 64 + hc] = cn;
  float ps = cn * sw[n * 64 + hc];
  float pr = cn * rw[n * 64 + hc];
#pragma unroll
  for (int o = 32; o; o >>= 1) { ps += __shfl_xor(ps, o); pr += __shfl_xor(pr, o); }
  if (hc == 0) {
    send[n * 256 + b] = 1.f / (1.f + __expf(-(ps + sb[n])));
    recv[n * 256 + b] = 1.f / (1.f + __expf(-(pr + rb[n])));
  }
#pragma unroll
  for (int kk = 0; kk < 8; kk++) {
    float pa = cn * aw[(n * 64 + hc) * 8 + kk];
#pragma unroll
    for (int o = 32; o; o >>= 1) pa += __shfl_xor(pa, o);
    if (hc == 0) ab[nb * 8 + kk] = pa + abb[n * 8 + kk];
  }
}

// ---------------- 8-node graph attention; accumulates msgsum (fp32 + f16 mirror)
__global__ __launch_bounds__(256) void attn_kernel(
    const float* __restrict__ qkv, const float* __restrict__ edge,
    const float* __restrict__ send, const float* __restrict__ recv,
    const float* __restrict__ ab, float* __restrict__ msgsum32, f16* __restrict__ msgsum16)
{
  int b = blockIdx.x, t = threadIdx.x;
  __shared__ float qs[8 * 520], ks[8 * 520], vs[8 * 520];
  __shared__ float sc[512];
  __shared__ float se[8], re[8], edg[64], abl[64];
  for (int i = t; i < 4096; i += 256) {
    int nn = i >> 9, c = i & 511, h = c >> 6, d = c & 63;
    long base = ((long)nn * 256 + b) * 1728 + c;
    int la = nn * 520 + h * 65 + d;
    qs[la] = qkv[base];
    ks[la] = qkv[base + 512];
    vs[la] = qkv[base + 1024];
  }
  if (t < 8) { se[t] = send[t * 256 + b]; re[t] = recv[t * 256 + b]; }
  if (t >= 64 && t < 128) edg[t - 64] = edge[t - 64];
  if (t >= 128 && t < 192) { int q = t - 128; abl[q] = ab[((long)(q >> 3) * 256 + b) * 8 + (q & 7)]; }
  __syncthreads();
  for (int idx = t; idx < 512; idx += 256) {
    int i = idx >> 6, j = (idx >> 3) & 7, h = idx & 7;
    const float* qp = &qs[i * 520 + h * 65];
    const float* kp = &ks[j * 520 + h * 65];
    float s = 0.f;
#pragma unroll
    for (int d = 0; d < 64; d++) s = fmaf(qp[d], kp[d], s);
    sc[idx] = s * 0.125f + edg[i * 8 + j] + abl[i * 8 + h];
  }
  __syncthreads();
  if (t < 64) {
    int i = t >> 3, h = t & 7;
    float mx = -1e30f;
#pragma unroll
    for (int j = 0; j < 8; j++) mx = fmaxf(mx, sc[(i << 6) + (j << 3) + h]);
    float e[8], sm = 0.f;
#pragma unroll
    for (int j = 0; j < 8; j++) { e[j] = __expf(sc[(i << 6) + (j << 3) + h] - mx); sm += e[j]; }
    float inv = re[i] / sm;
#pragma unroll
    for (int j = 0; j < 8; j++) sc[(i << 6) + (j << 3) + h] = e[j] * inv * se[j];
  }
  __syncthreads();
  for (int idx = t; idx < 4096; idx += 256) {
    int i = idx >> 9, c = idx & 511, h = c >> 6, d = c & 63;
    float s = 0.f;
#pragma unroll
    for (int j = 0; j < 8; j++) s = fmaf(sc[(i << 6) + (j << 3) + h], vs[j * 520 + h * 65 + d], s);
    long oi = ((long)i * 256 + b) * 512 + c;
    float nv = msgsum32[oi] + s;
    msgsum32[oi] = nv;
    msgsum16[oi] = (f16)nv;
  }
}

// ---------------- h = (1-g)*h + g*cand; h fp32 + f16 mirror in cat16
__global__ __launch_bounds__(256) void hupdate_kernel(
    float* __restrict__ h32, f16* __restrict__ cat16, const float* __restrict__ gc)
{
  long idx = (long)blockIdx.x * 256 + threadIdx.x; // 1,048,576
  long nb = idx >> 9; int m = (int)(idx & 511);
  float g = gc[nb * 1024 + m];
  float cd = gc[nb * 1024 + 512 + m];
  float h = h32[idx];
  float nh = (1.f - g) * h + g * cd;
  h32[idx] = nh;
  cat16[nb * 1536 + m] = (f16)nh;
}

// ---------------- classifier (fp32)
__global__ __launch_bounds__(256) void cls_kernel(
    const float* __restrict__ h32, const float* __restrict__ wcls,
    const float* __restrict__ bcls, float* __restrict__ out)
{
  __shared__ float As[2][512];
  int n = blockIdx.x >> 7, r0 = (blockIdx.x & 127) * 2;
  int t = threadIdx.x;
  for (int i = t; i < 1024; i += 256)
    As[i >> 9][i & 511] = h32[((long)(n * 256 + r0 + (i >> 9))) * 512 + (i & 511)];
  __syncthreads();
  int r = r0 + (t >> 7), c = t & 127;
  if (c < 100) {
    const float* wp = wcls + (long)n * 512 * 100 + c;
    const float* arow = As[t >> 7];
    float acc = bcls[n * 100 + c];
#pragma unroll 4
    for (int k = 0; k < 512; k++) acc = fmaf(arow[k], wp[k * 100], acc);
    out[((long)(n * 256 + r)) * 100 + c] = acc;
  }
}

extern "C" void kernel_launch(void* const* d_in, const int* in_sizes, int n_in,
                              void* d_out, int out_size, void* d_ws, size_t ws_size,
                              hipStream_t stream)
{
  (void)in_sizes; (void)n_in; (void)out_size;
  const float* x        = (const float*)d_in[0];
  const float* conv1_w  = (const float*)d_in[1];
  const float* conv1_b  = (const float*)d_in[2];
  const float* conv2_w  = (const float*)d_in[3];
  const float* conv2_b  = (const float*)d_in[4];
  const float* feat_w   = (const float*)d_in[5];
  const float* feat_b   = (const float*)d_in[6];
  const float* ctrl_wi  = (const float*)d_in[7];
  const float* ctrl_wh  = (const float*)d_in[8];
  const float* ctrl_bi  = (const float*)d_in[9];
  const float* ctrl_bh  = (const float*)d_in[10];
  const float* send_w   = (const float*)d_in[11];
  const float* send_b   = (const float*)d_in[12];
  const float* recv_w   = (const float*)d_in[13];
  const float* recv_b   = (const float*)d_in[14];
  const float* abias_w  = (const float*)d_in[15];
  const float* abias_b  = (const float*)d_in[16];
  const float* wq       = (const float*)d_in[17];
  const float* wk       = (const float*)d_in[18];
  const float* wv       = (const float*)d_in[19];
  const float* wo       = (const float*)d_in[20];
  const float* bo       = (const float*)d_in[21];
  const float* edge     = (const float*)d_in[22];
  const float* wr       = (const float*)d_in[23];
  const float* br       = (const float*)d_in[24];
  const float* wg       = (const float*)d_in[25];
  const float* bg       = (const float*)d_in[26];
  const float* wc       = (const float*)d_in[27];
  const float* bc       = (const float*)d_in[28];
  const float* wcls     = (const float*)d_in[29];
  const float* bcls     = (const float*)d_in[30];

  // ---- workspace layout
  float* f32b = (float*)d_ws;
  float* h32      = f32b;             // 1,048,576
  float* qkvb     = f32b + 1048576;   // 3,538,944
  float* gc       = f32b + 4587520;   // 2,097,152
  float* msgsum32 = f32b + 6684672;   // 1,048,576
  float* cs       = f32b + 7733248;   // 131,072
  float* sendb    = f32b + 7864320;   // 2,048
  float* recvb    = f32b + 7866368;   // 2,048
  float* abb      = f32b + 7868416;   // 16,384
  float* bor32    = f32b + 7884800;   // 4,096
  f16* hb = (f16*)(f32b + 7888896);
  f16* pooled16 = hb;                 // 262,144
  f16* cat16    = hb + 262144;        // 3,145,728  [h|feats|readout]
  f16* msgsum16 = hb + 3407872;       // 1,048,576
  f16* wqT      = hb + 4456448;       // 2,097,152
  f16* wkT      = hb + 6553600;       // 2,097,152
  f16* wvT      = hb + 8650752;       // 2,097,152
  f16* wiT      = hb + 10747904;      // 786,432
  f16* featwT   = hb + 11534336;      // 524,288
  f16* wrT      = hb + 12058624;      // 2,097,152 (x0.125)
  f16* wgT      = hb + 14155776;      // 6,291,456
  f16* wcT      = hb + 20447232;      // 6,291,456
  f16* c2wp     = hb + 26738688;      // 589,824
  f16* wo16     = hb + 27328512;      // 2,097,152
  f16* worT     = hb + 29425664;      // 2,097,152
  // total = 31,555,584 + 63,045,632 = 94,601,216 bytes
  if (ws_size < 94601216ull) return;

  hipMemsetAsync(cs, 0, 131072 * 4, stream);
  hipMemsetAsync(msgsum32, 0, 1048576 * 4, stream);

  // ---- one-time weight prep
  tw64_kernel<<<dim3(8, 8, 8), 256, 0, stream>>>(wq, wqT, 512, 512, 1.f);
  tw64_kernel<<<dim3(8, 8, 8), 256, 0, stream>>>(wk, wkT, 512, 512, 1.f);
  tw64_kernel<<<dim3(8, 8, 8), 256, 0, stream>>>(wv, wvT, 512, 512, 1.f);
  tw64_kernel<<<dim3(3, 8, 8), 256, 0, stream>>>(ctrl_wi, wiT, 512, 192, 1.f);
  tw64_kernel<<<dim3(8, 2, 8), 256, 0, stream>>>(feat_w, featwT, 128, 512, 1.f);
  tw64_kernel<<<dim3(8, 8, 8), 256, 0, stream>>>(wr, wrT, 512, 512, 0.125f);
  tw64_kernel<<<dim3(8, 24, 8), 256, 0, stream>>>(wg, wgT, 1536, 512, 1.f);
  tw64_kernel<<<dim3(8, 24, 8), 256, 0, stream>>>(wc, wcT, 1536, 512, 1.f);
  cconv_kernel<<<1024, 256, 0, stream>>>(wo, wo16);
  c2wconv_kernel<<<2304, 256, 0, stream>>>(conv2_w, c2wp);
  bor_kernel<<<dim3(2, 8), 256, 0, stream>>>(bo, wr, bor32);
  // worT[m][k] = sum_c wr[c][m]*0.125 * wo[k][c]  (= ((wo@wr)/8)^T)
  {
    SegsM s{};
    s.BT[0] = wo16; s.sBT[0] = 262144;
    gemmf16_kernel<<<dim3(8, 8, 8), 256, 0, stream>>>(
        wrT, 262144L, 512, s, 512, 0.f,
        nullptr, 0L, 0, worT, nullptr, 262144L, 512);
  }

  // ---- fused feature extraction -> pooled16
  convfused_kernel<<<dim3(256, 8), 256, 0, stream>>>(x, conv1_w, conv1_b, c2wp, conv2_b, pooled16);

  // feats = relu(pooled @ feat_w + b) -> cat16[512:1024]; h-init -> h32 + cat16[0:512]
  {
    SegsM s{};
    s.BT[0] = featwT; s.sBT[0] = 65536; s.bias[0] = feat_b; s.sBias[0] = 512; s.act[0] = 1;
    gemmf16_kernel<<<dim3(8, 4, 8), 256, 0, stream>>>(
        pooled16, 32768L, 128, s, 128, 0.f,
        h32, 131072L, 512, cat16 + 512, cat16, 393216L, 1536);
  }

  for (int step = 0; step < 3; step++) {
    // q|k|v|gi = h @ {wq,wk,wv,ctrl_wi}
    {
      SegsM s{};
      s.BT[0] = wqT; s.BT[1] = wkT; s.BT[2] = wvT; s.BT[3] = wiT;
      s.sBT[0] = 262144; s.sBT[1] = 262144; s.sBT[2] = 262144; s.sBT[3] = 98304;
      s.bias[3] = ctrl_bi; s.sBias[3] = 192;
      gemmf16_kernel<<<dim3(27, 4, 8), 256, 0, stream>>>(
          cat16, 393216L, 1536, s, 512, 0.f,
          qkvb, 442368L, 1728, nullptr, nullptr, 0L, 0);
    }
    gru_kernel<<<dim3(256, 8), 64, 0, stream>>>(
        qkvb, ctrl_wh, ctrl_bh, cs, send_w, send_b, recv_w, recv_b,
        abias_w, abias_b, sendb, recvb, abb);
    attn_kernel<<<256, 256, 0, stream>>>(qkvb, edge, sendb, recvb, abb, msgsum32, msgsum16);
    // readout = msgsum @ worT + (step+1)*bor + br -> cat16[1024:1536]
    {
      SegsM s{};
      s.BT[0] = worT; s.sBT[0] = 262144;
      s.bias[0] = br; s.sBias[0] = 512;
      s.bias2[0] = bor32; s.sBias2[0] = 512;
      gemmf16_kernel<<<dim3(8, 4, 8), 256, 0, stream>>>(
          msgsum16, 131072L, 512, s, 512, (float)(step + 1),
          nullptr, 0L, 0, cat16 + 1024, nullptr, 393216L, 1536);
    }
    // g|cand = sigmoid/tanh(cat16 @ [wg|wc] + [bg|bc])
    {
      SegsM s{};
      s.BT[0] = wgT; s.BT[1] = wcT;
      s.sBT[0] = 786432; s.sBT[1] = 786432;
      s.bias[0] = bg; s.bias[1] = bc; s.sBias[0] = 512; s.sBias[1] = 512;
      s.act[0] = 2; s.act[1] = 3;
      gemmf16_kernel<<<dim3(16, 4, 8), 256, 0, stream>>>(
          cat16, 393216L, 1536, s, 1536, 0.f,
          gc, 262144L, 1024, nullptr, nullptr, 0L, 0);
    }
    hupdate_kernel<<<4096, 256, 0, stream>>>(h32, cat16, gc);
  }
  cls_kernel<<<1024, 256, 0, stream>>>(h32, wcls, bcls, (float*)d_out);
}

// Round 4
// 410.497 us; speedup vs baseline: 4.2042x; 1.1860x over previous
//
#include <hip/hip_runtime.h>
#include <hip/hip_bf16.h>

// DNBN system, f16-MFMA, round 4.
// N=8, B=256, M=512, C=512, NH=8, DH=64, S=8, HC=64, T=3, OUT=100.
// T(3) < S(8) -> FIFO never evicts -> buf.mean == msum/8.
// Round 4: conv1 via MFMA inside fused conv kernel; readout GEMM folded
// into wgc GEMM via Weff=(wo@wr/8)@wg_r precompute; dual-source K GEMM.

typedef _Float16 f16;
typedef _Float16 f16x8 __attribute__((ext_vector_type(8)));
typedef _Float16 f16x4 __attribute__((ext_vector_type(4)));
typedef float f32x4 __attribute__((ext_vector_type(4)));

#define GLOAD_LDS16(gsrc, ldst)                                                   \
  __builtin_amdgcn_global_load_lds(                                               \
      (const __attribute__((address_space(1))) void*)(gsrc),                      \
      (__attribute__((address_space(3))) void*)(ldst), 16, 0, 0)

// ---------------- transpose+convert tile body: [K][N] f32 -> [N][K] f16 (scaled)
__device__ __forceinline__ void tw64_body(
    const float* __restrict__ s, f16* __restrict__ d, int K, int N, float scale,
    int n0, int k0, int t)
{
  __shared__ float tile[64][65];
#pragma unroll
  for (int p = 0; p < 4; p++) {
    int idx = t + p * 256;
    int kk = idx >> 4, nq = (idx & 15) * 4;
    float4 v = *(const float4*)&s[(long)(k0 + kk) * N + n0 + nq];
    tile[kk][nq] = v.x; tile[kk][nq + 1] = v.y; tile[kk][nq + 2] = v.z; tile[kk][nq + 3] = v.w;
  }
  __syncthreads();
#pragma unroll
  for (int p = 0; p < 2; p++) {
    int idx = t + p * 256;
    int nn = idx >> 3, kc = (idx & 7) * 8;
    f16 o[8];
#pragma unroll
    for (int i = 0; i < 8; i++) o[i] = (f16)(tile[kc + i][nn] * scale);
    *(f16x8*)&d[(long)(n0 + nn) * K + k0 + kc] = *(const f16x8*)o;
  }
}

__global__ __launch_bounds__(256) void tw64_kernel(
    const float* __restrict__ src, f16* __restrict__ dst, int K, int N, float scale)
{
  int z = blockIdx.z;
  tw64_body(src + (long)z * K * N, dst + (long)z * N * K, K, N, scale,
            blockIdx.x * 64, blockIdx.y * 64, threadIdx.x);
}

// wq|wk|wv|wi batched transpose: z = sel*8 + e
__global__ __launch_bounds__(256) void twmulti4_kernel(
    const float* __restrict__ wq, const float* __restrict__ wk,
    const float* __restrict__ wv, const float* __restrict__ wi, f16* __restrict__ wqT)
{
  int z = blockIdx.z, sel = z >> 3, e = z & 7;
  int N = (sel < 3) ? 512 : 192;
  int n0 = blockIdx.x * 64;
  if (n0 >= N) return;
  const float* src = (sel == 0) ? wq : (sel == 1) ? wk : (sel == 2) ? wv : wi;
  f16* dst = (sel < 3) ? (wqT + (long)sel * 2097152 + (long)e * 262144)
                       : (wqT + 3L * 2097152 + (long)e * 98304);
  tw64_body(src + (long)e * 512 * N, dst, 512, N, 1.f, n0, blockIdx.y * 64, threadIdx.x);
}

// wg|wc batched transpose: z = sel*8 + e
__global__ __launch_bounds__(256) void twmulti2_kernel(
    const float* __restrict__ wg, const float* __restrict__ wc, f16* __restrict__ wgT)
{
  int z = blockIdx.z, sel = z >> 3, e = z & 7;
  const float* src = sel ? wc : wg;
  f16* dst = wgT + (long)sel * 6291456 + (long)e * 786432;
  tw64_body(src + (long)e * 1536 * 512, dst, 1536, 512, 1.f,
            blockIdx.x * 64, blockIdx.y * 64, threadIdx.x);
}

// ---------------- straight f32 -> f16 convert (wo)
__global__ __launch_bounds__(256) void cconv_kernel(const float* __restrict__ s, f16* __restrict__ d)
{
  long i = ((long)blockIdx.x * 256 + threadIdx.x) * 8;
  float4 a = *(const float4*)&s[i];
  float4 b = *(const float4*)&s[i + 4];
  f16 o[8] = {(f16)a.x, (f16)a.y, (f16)a.z, (f16)a.w, (f16)b.x, (f16)b.y, (f16)b.z, (f16)b.w};
  *(f16x8*)&d[i] = *(const f16x8*)o;
}

// ---------------- conv2 weight permute: [8][128co][64ci][3][3] -> [8][128co][9tap][64ci] f16
__global__ __launch_bounds__(256) void c2wconv_kernel(const float* __restrict__ src, f16* __restrict__ dst)
{
  long i = (long)blockIdx.x * 256 + threadIdx.x; // 589824
  int ci = i & 63; long r = i >> 6; int tap = r % 9; r /= 9; int co = r & 127; int n = (int)(r >> 7);
  dst[i] = (f16)src[(((long)(n * 128 + co) * 64 + ci) * 9) + tap];
}

// ---------------- conv1 weight prep: [8][64co][27k] -> [8][4slot][64co][8] f16 (k padded to 32)
__global__ __launch_bounds__(256) void w1prep_kernel(const float* __restrict__ src, f16* __restrict__ dst)
{
  int i = blockIdx.x * 256 + threadIdx.x; // 16384
  int j = i & 7, co = (i >> 3) & 63, slot = (i >> 9) & 3, e = i >> 11;
  int k = slot * 8 + j;
  dst[i] = (f16)((k < 27) ? src[(long)e * 1728 + co * 27 + k] : 0.f);
}

// ---------------- bor[n][m] = (bo @ wr)[m] / 8
__global__ __launch_bounds__(256) void bor_kernel(
    const float* __restrict__ bo, const float* __restrict__ wr, float* __restrict__ bor)
{
  int n = blockIdx.y, m = blockIdx.x * 256 + threadIdx.x; // grid (2,8)
  const float* w = wr + (long)n * 262144;
  const float* b = bo + n * 512;
  float s = 0.f;
  for (int c = 0; c < 512; c++) s = fmaf(b[c], w[(long)c * 512 + m], s);
  bor[n * 512 + m] = s * 0.125f;
}

// ---------------- bias folding through wg_r/wc_r:
// bgr = bg + br@wg_r; vg2 = bor@wg_r; bcr = bc + br@wc_r; vc2 = bor@wc_r
__global__ __launch_bounds__(256) void biasfold_kernel(
    const float* __restrict__ wg, const float* __restrict__ wc,
    const float* __restrict__ bg, const float* __restrict__ bc,
    const float* __restrict__ br, const float* __restrict__ bor32,
    float* __restrict__ bgr, float* __restrict__ vg2,
    float* __restrict__ bcr, float* __restrict__ vc2)
{
  int n = blockIdx.y, o = blockIdx.x * 256 + threadIdx.x; // grid (2,8)
  const float* wgr = wg + (long)n * 786432 + 1024L * 512;
  const float* wcr = wc + (long)n * 786432 + 1024L * 512;
  float s1g = 0.f, s2g = 0.f, s1c = 0.f, s2c = 0.f;
  for (int m = 0; m < 512; m++) {
    float brm = br[n * 512 + m], borm = bor32[n * 512 + m];
    float wgv = wgr[(long)m * 512 + o], wcv = wcr[(long)m * 512 + o];
    s1g = fmaf(brm, wgv, s1g); s2g = fmaf(borm, wgv, s2g);
    s1c = fmaf(brm, wcv, s1c); s2c = fmaf(borm, wcv, s2c);
  }
  bgr[n * 512 + o] = bg[n * 512 + o] + s1g; vg2[n * 512 + o] = s2g;
  bcr[n * 512 + o] = bc[n * 512 + o] + s1c; vc2[n * 512 + o] = s2c;
}

// ---------------- fused conv1(MFMA)+conv2(MFMA)+pool: one block per (b,e)
__global__ __launch_bounds__(256) void convfused_kernel(
    const float* __restrict__ x, const f16* __restrict__ w1p, const float* __restrict__ b1,
    const f16* __restrict__ w2p, const float* __restrict__ b2, f16* __restrict__ pooled16)
{
  __shared__ __align__(16) char lds[70784];
  // region A [0,32768): phase0-2 = xpatch[4slot][256pix][8] (16KB) + ws1[4slot][64co][8] (4KB)
  //                      phase3  = Asub 2 x [128co][64ci] (32KB)
  f16* xpatch = (f16*)lds;
  f16* ws1 = (f16*)(lds + 16384);
  f16* Asub = (f16*)lds;
  f16* h1s = (f16*)(lds + 32768);      // [289 pix][64 ci], granule g at slot g^fs(p)
  float* xs = (float*)(lds + 32768);   // aliases h1s (dead before h1s written)
  float* red = (float*)(lds + 69760);  // pool scratch; also aliased by bs1
  float* bs1 = (float*)(lds + 69760);

  int b = blockIdx.x, e = blockIdx.y;
  int t = threadIdx.x, w = t >> 6, l = t & 63;

  // phase 0: stage x[b] (12KB) + w1p[e] (4KB) + b1
  const float* xb = x + (long)b * 3072;
#pragma unroll
  for (int c0 = 0; c0 < 3; c0++) {
    int c = w * 3 + c0;
    GLOAD_LDS16(xb + c * 256 + l * 4, (char*)xs + c * 1024);
  }
  GLOAD_LDS16(w1p + (long)e * 2048 + w * 512 + l * 8, (char*)ws1 + w * 1024);
  if (t < 64) bs1[t] = b1[e * 64 + t];
  asm volatile("s_waitcnt vmcnt(0)" ::: "memory");
  __syncthreads();

  // phase 1: im2col patch build; thread t = output pixel (oy,ox)
  {
    int oy = t >> 4, ox = t & 15;
    f16 pv[32];
#pragma unroll
    for (int q = 27; q < 32; q++) pv[q] = (f16)0.f;
#pragma unroll
    for (int ci = 0; ci < 3; ci++)
#pragma unroll
      for (int ky = 0; ky < 3; ky++) {
        int iy = oy * 2 + ky;
#pragma unroll
        for (int kx = 0; kx < 3; kx++) {
          int ix = ox * 2 + kx;
          pv[ci * 9 + ky * 3 + kx] =
              (f16)((iy < 32 && ix < 32) ? xs[ci * 1024 + iy * 32 + ix] : 0.f);
        }
      }
#pragma unroll
    for (int c = 0; c < 4; c++) *(f16x8*)&xpatch[c * 2048 + t * 8] = *(const f16x8*)&pv[c * 8];
  }
  __syncthreads();

  // phase 2: conv1 MFMA  D[co 0..63][pix 0..255], wave w owns pix w*64..+63
  {
    int pw = w * 64;
    f16x8 a1[4], b1f[4];
#pragma unroll
    for (int i = 0; i < 4; i++)
      a1[i] = *(const f16x8*)&ws1[(l >> 4) * 512 + (i * 16 + (l & 15)) * 8];
#pragma unroll
    for (int jj = 0; jj < 4; jj++)
      b1f[jj] = *(const f16x8*)&xpatch[(l >> 4) * 2048 + (pw + jj * 16 + (l & 15)) * 8];
    f32x4 acc1[4][4];
#pragma unroll
    for (int i = 0; i < 4; i++)
#pragma unroll
      for (int jj = 0; jj < 4; jj++)
        acc1[i][jj] = __builtin_amdgcn_mfma_f32_16x16x32_f16(
            a1[i], b1f[jj], (f32x4){0.f, 0.f, 0.f, 0.f}, 0, 0, 0);
    // epilogue: relu(+bias), write into swizzled h1s
#pragma unroll
    for (int i = 0; i < 4; i++) {
      int co0 = i * 16 + ((l >> 4) << 2);
      float bi0 = bs1[co0], bi1 = bs1[co0 + 1], bi2 = bs1[co0 + 2], bi3 = bs1[co0 + 3];
#pragma unroll
      for (int jj = 0; jj < 4; jj++) {
        int p2 = pw + jj * 16 + (l & 15);
        int oy2 = p2 >> 4, ox2 = p2 & 15;
        int p = oy2 * 17 + ox2;
        int fs = ((ox2 >> 1) + oy2) & 7;
        int slot = (co0 >> 3) ^ fs;
        f16x4 v;
        v[0] = (f16)fmaxf(acc1[i][jj][0] + bi0, 0.f);
        v[1] = (f16)fmaxf(acc1[i][jj][1] + bi1, 0.f);
        v[2] = (f16)fmaxf(acc1[i][jj][2] + bi2, 0.f);
        v[3] = (f16)fmaxf(acc1[i][jj][3] + bi3, 0.f);
        *(f16x4*)&h1s[p * 64 + slot * 8 + (co0 & 7)] = v;
      }
    }
  }
  if (t < 33) { // zero guard ring (row 16 + col 16)
    int gy = (t < 17) ? 16 : (t - 17);
    int gx = (t < 17) ? t : 16;
    int p = gy * 17 + gx;
    f16x8 zz = {};
#pragma unroll
    for (int g = 0; g < 8; g++) *(f16x8*)&h1s[p * 64 + g * 8] = zz;
  }
  __syncthreads(); // xpatch/ws1 reads done (Asub reusable); h1s visible

  // phase 3: conv2 MFMA over 9 taps, A(weights) double-buffered
  int waveR = w >> 1, waveC = w & 1;
  const f16* wbase = w2p + (long)e * 73728;
  auto stageA = [&](int buf, int tap) {
#pragma unroll
    for (int c = 0; c < 4; c++) {
      int ch = w * 4 + c;
      int co = ch * 8 + (l >> 3);
      int g = (l & 7) ^ (co & 7);
      GLOAD_LDS16(wbase + ((long)co * 9 + tap) * 64 + g * 8, &Asub[buf * 8192 + ch * 512]);
    }
  };
  stageA(0, 0);
  asm volatile("s_waitcnt vmcnt(0)" ::: "memory");
  __syncthreads();

  f32x4 acc[4][2];
#pragma unroll
  for (int i = 0; i < 4; i++) {
    acc[i][0] = (f32x4){0.f, 0.f, 0.f, 0.f};
    acc[i][1] = (f32x4){0.f, 0.f, 0.f, 0.f};
  }
  int cur = 0;
  for (int tap = 0; tap < 9; tap++) {
    if (tap < 8) stageA(cur ^ 1, tap + 1);
    int ky = tap / 3, kx = tap - ky * 3;
#pragma unroll
    for (int kk = 0; kk < 2; kk++) {
      f16x8 af[4], bf[2];
#pragma unroll
      for (int i = 0; i < 4; i++) {
        int row = waveR * 64 + i * 16 + (l & 15);
        int blk = (kk * 4 + (l >> 4)) ^ (row & 7);
        af[i] = *(const f16x8*)&Asub[cur * 8192 + row * 64 + blk * 8];
      }
#pragma unroll
      for (int j = 0; j < 2; j++) {
        int sp = waveC * 32 + j * 16 + (l & 15);
        int iy = (sp >> 3) * 2 + ky, ix = (sp & 7) * 2 + kx;
        int fs = ((ix >> 1) + iy) & 7;
        int blk = (kk * 4 + (l >> 4)) ^ fs;
        bf[j] = *(const f16x8*)&h1s[(iy * 17 + ix) * 64 + blk * 8];
      }
#pragma unroll
      for (int i = 0; i < 4; i++)
#pragma unroll
        for (int j = 0; j < 2; j++)
          acc[i][j] = __builtin_amdgcn_mfma_f32_16x16x32_f16(af[i], bf[j], acc[i][j], 0, 0, 0);
    }
    if (tap < 8) {
      asm volatile("s_waitcnt vmcnt(0)" ::: "memory");
      __syncthreads();
      cur ^= 1;
    }
  }
  // epilogue: relu(acc+bias) summed over 64 spatial cols, /64
  __syncthreads(); // bs1 alias: conv1 bias reads long done; safe to reuse as red
  const float* bn2 = b2 + e * 128;
#pragma unroll
  for (int i = 0; i < 4; i++) {
#pragma unroll
    for (int reg = 0; reg < 4; reg++) {
      int row = waveR * 64 + i * 16 + ((l >> 4) << 2) + reg;
      float bi = bn2[row];
      float s = fmaxf(acc[i][0][reg] + bi, 0.f) + fmaxf(acc[i][1][reg] + bi, 0.f);
      s += __shfl_xor(s, 1); s += __shfl_xor(s, 2);
      s += __shfl_xor(s, 4); s += __shfl_xor(s, 8);
      if ((l & 15) == 0) red[waveC * 128 + row] = s;
    }
  }
  __syncthreads();
  if (t < 128) {
    float v = (red[t] + red[128 + t]) * (1.f / 64.f);
    pooled16[((long)e * 256 + b) * 128 + t] = (f16)v;
  }
}

// ---------------- segmented f16-MFMA GEMM: 64x64 tile, 4 waves, BK=64, dbuf,
// optional dual source: kt >= ktSw reads A2/BT2 (second K range)
struct SegsM {
  const f16* BT[4];
  const f16* BT2[4];
  const float* bias[4];
  const float* bias2[4];
  long sBT[4];
  long sBT2[4];
  long sBias[4];
  long sBias2[4];
  int act[4]; // 0 none, 1 relu, 2 sigmoid, 3 tanh
};

__global__ __launch_bounds__(256) void gemmf16_kernel(
    const f16* __restrict__ A, long sA, int lda,
    const f16* __restrict__ A2, long sA2, int lda2, int ktSw,
    SegsM segs, int K, int ldbA, int ldbB, float b2scale,
    float* __restrict__ C32, long sC32, int ldc32,
    f16* __restrict__ C16, f16* __restrict__ C16b, long sC16, int ldc16)
{
  __shared__ __align__(16) f16 Asub[2][64 * 64];
  __shared__ __align__(16) f16 Bsub[2][64 * 64];
  int z = blockIdx.z;
  int rowBase = blockIdx.y * 64;
  int vcBase = blockIdx.x * 64;
  int seg = vcBase >> 9;
  int lcBase = vcBase & 511;
  const f16* An = A + (long)z * sA + (long)rowBase * lda;
  const f16* A2n = A2 ? A2 + (long)z * sA2 + (long)rowBase * lda2 : nullptr;
  const f16* BTn = segs.BT[seg] + (long)z * segs.sBT[seg] + (long)lcBase * ldbA;
  const f16* BT2n = segs.BT2[seg] ? segs.BT2[seg] + (long)z * segs.sBT2[seg] + (long)lcBase * ldbB : nullptr;
  const float* biasN = segs.bias[seg] ? segs.bias[seg] + (long)z * segs.sBias[seg] : nullptr;
  const float* bias2N = segs.bias2[seg] ? segs.bias2[seg] + (long)z * segs.sBias2[seg] : nullptr;
  int act = segs.act[seg];
  int t = threadIdx.x, w = t >> 6, l = t & 63;
  int waveR = w >> 1, waveC = w & 1;
  f32x4 acc[2][2];
#pragma unroll
  for (int i = 0; i < 2; i++) {
    acc[i][0] = (f32x4){0.f, 0.f, 0.f, 0.f};
    acc[i][1] = (f32x4){0.f, 0.f, 0.f, 0.f};
  }
  auto stage = [&](int buf, int kt) {
    const f16* ab;
    const f16* bb;
    int stA, stB;
    if (kt < ktSw) {
      int k0 = kt << 6;
      ab = An + k0; bb = BTn + k0; stA = lda; stB = ldbA;
    } else {
      int k0 = (kt - ktSw) << 6;
      ab = A2n + k0; bb = BT2n + k0; stA = lda2; stB = ldbB;
    }
#pragma unroll
    for (int c = 0; c < 2; c++) {
      int ch = w * 2 + c;
      int row = ch * 8 + (l >> 3);
      int g = (l & 7) ^ (row & 7);
      GLOAD_LDS16(ab + (long)row * stA + g * 8, &Asub[buf][ch * 512]);
    }
#pragma unroll
    for (int c = 0; c < 2; c++) {
      int ch = w * 2 + c;
      int col = ch * 8 + (l >> 3);
      int g = (l & 7) ^ (col & 7);
      GLOAD_LDS16(bb + (long)col * stB + g * 8, &Bsub[buf][ch * 512]);
    }
  };
  int nk = K >> 6;
  stage(0, 0);
  asm volatile("s_waitcnt vmcnt(0)" ::: "memory");
  __syncthreads();
  int cur = 0;
  for (int kt = 0; kt < nk; kt++) {
    if (kt + 1 < nk) stage(cur ^ 1, kt + 1);
#pragma unroll
    for (int kk = 0; kk < 2; kk++) {
      f16x8 af[2], bf[2];
#pragma unroll
      for (int i = 0; i < 2; i++) {
        int row = waveR * 32 + i * 16 + (l & 15);
        int blk = (kk * 4 + (l >> 4)) ^ (row & 7);
        af[i] = *(const f16x8*)&Asub[cur][row * 64 + blk * 8];
      }
#pragma unroll
      for (int j = 0; j < 2; j++) {
        int col = waveC * 32 + j * 16 + (l & 15);
        int blk = (kk * 4 + (l >> 4)) ^ (col & 7);
        bf[j] = *(const f16x8*)&Bsub[cur][col * 64 + blk * 8];
      }
#pragma unroll
      for (int i = 0; i < 2; i++)
#pragma unroll
        for (int j = 0; j < 2; j++)
          acc[i][j] = __builtin_amdgcn_mfma_f32_16x16x32_f16(af[i], bf[j], acc[i][j], 0, 0, 0);
    }
    if (kt + 1 < nk) {
      asm volatile("s_waitcnt vmcnt(0)" ::: "memory");
      __syncthreads();
      cur ^= 1;
    }
  }
  int lcW = lcBase + waveC * 32;
#pragma unroll
  for (int i = 0; i < 2; i++) {
    int rb = rowBase + waveR * 32 + i * 16 + ((l >> 4) << 2);
#pragma unroll
    for (int j = 0; j < 2; j++) {
      int lc = lcW + j * 16 + (l & 15);
      int vc = (seg << 9) + lc;
      float bv = biasN ? biasN[lc] : 0.f;
      if (bias2N) bv += b2scale * bias2N[lc];
#pragma unroll
      for (int reg = 0; reg < 4; reg++) {
        float v = acc[i][j][reg] + bv;
        if (act == 1) v = fmaxf(v, 0.f);
        else if (act == 2) v = 1.f / (1.f + __expf(-v));
        else if (act == 3) v = tanhf(v);
        long rr = rb + reg;
        if (C32) C32[(long)z * sC32 + rr * ldc32 + vc] = v;
        if (C16) C16[(long)z * sC16 + rr * ldc16 + vc] = (f16)v;
        if (C16b) C16b[(long)z * sC16 + rr * ldc16 + vc] = (f16)v;
      }
    }
  }
}

// ---------------- GRU controller + send/recv/ab gates (fp32)
__global__ __launch_bounds__(64) void gru_kernel(
    const float* __restrict__ qkv, const float* __restrict__ wh, const float* __restrict__ bh,
    float* __restrict__ cs, const float* __restrict__ sw, const float* __restrict__ sb,
    const float* __restrict__ rw, const float* __restrict__ rb,
    const float* __restrict__ aw, const float* __restrict__ abb,
    float* __restrict__ send, float* __restrict__ recv, float* __restrict__ ab)
{
  int b = blockIdx.x, n = blockIdx.y, hc = threadIdx.x;
  __shared__ float csh[64];
  long nb = (long)n * 256 + b;
  float c0 = cs[nb * 64 + hc];
  csh[hc] = c0;
  __syncthreads();
  const float* whn = wh + (long)n * 64 * 192;
  float g0 = bh[n * 192 + hc], g1 = bh[n * 192 + 64 + hc], g2 = bh[n * 192 + 128 + hc];
  for (int k = 0; k < 64; k++) {
    float cv = csh[k];
    g0 = fmaf(cv, whn[k * 192 + hc], g0);
    g1 = fmaf(cv, whn[k * 192 + 64 + hc], g1);
    g2 = fmaf(cv, whn[k * 192 + 128 + hc], g2);
  }
  const float* gi = qkv + nb * 1728 + 1536;
  float iz = gi[hc], ir = gi[64 + hc], inn = gi[128 + hc];
  float zg = 1.f / (1.f + __expf(-(iz + g0)));
  float rg = 1.f / (1.f + __expf(-(ir + g1)));
  float ng = tanhf(inn + rg * g2);
  float cn = (1.f - zg) * ng + zg * c0;
  cs[nb * 64 + hc] = cn;
  float ps = cn * sw[n * 64 + hc];
  float pr = cn * rw[n * 64 + hc];
#pragma unroll
  for (int o = 32; o; o >>= 1) { ps += __shfl_xor(ps, o); pr += __shfl_xor(pr, o); }
  if (hc == 0) {
    send[n * 256 + b] = 1.f / (1.f + __expf(-(ps + sb[n])));
    recv[n * 256 + b] = 1.f / (1.f + __expf(-(pr + rb[n])));
  }
#pragma unroll
  for (int kk = 0; kk < 8; kk++) {
    float pa = cn * aw[(n * 64 + hc) * 8 + kk];
#pragma unroll
    for (int o = 32; o; o >>= 1) pa += __shfl_xor(pa, o);
    if (hc == 0) ab[nb * 8 + kk] = pa + abb[n * 8 + kk];
  }
}

// ---------------- 8-node graph attention; accumulates msgsum (fp32 + f16 mirror)
__global__ __launch_bounds__(256) void attn_kernel(
    const float* __restrict__ qkv, const float* __restrict__ edge,
    const float* __restrict__ send, const float* __restrict__ recv,
    const float* __restrict__ ab, float* __restrict__ msgsum32, f16* __restrict__ msgsum16)
{
  int b = blockIdx.x, t = threadIdx.x;
  __shared__ float qs[8 * 520], ks[8 * 520], vs[8 * 520];
  __shared__ float sc[512];
  __shared__ float se[8], re[8], edg[64], abl[64];
  for (int i = t; i < 4096; i += 256) {
    int nn = i >> 9, c = i & 511, h = c >> 6, d = c & 63;
    long base = ((long)nn * 256 + b) * 1728 + c;
    int la = nn * 520 + h * 65 + d;
    qs[la] = qkv[base];
    ks[la] = qkv[base + 512];
    vs[la] = qkv[base + 1024];
  }
  if (t < 8) { se[t] = send[t * 256 + b]; re[t] = recv[t * 256 + b]; }
  if (t >= 64 && t < 128) edg[t - 64] = edge[t - 64];
  if (t >= 128 && t < 192) { int q = t - 128; abl[q] = ab[((long)(q >> 3) * 256 + b) * 8 + (q & 7)]; }
  __syncthreads();
  for (int idx = t; idx < 512; idx += 256) {
    int i = idx >> 6, j = (idx >> 3) & 7, h = idx & 7;
    const float* qp = &qs[i * 520 + h * 65];
    const float* kp = &ks[j * 520 + h * 65];
    float s = 0.f;
#pragma unroll
    for (int d = 0; d < 64; d++) s = fmaf(qp[d], kp[d], s);
    sc[idx] = s * 0.125f + edg[i * 8 + j] + abl[i * 8 + h];
  }
  __syncthreads();
  if (t < 64) {
    int i = t >> 3, h = t & 7;
    float mx = -1e30f;
#pragma unroll
    for (int j = 0; j < 8; j++) mx = fmaxf(mx, sc[(i << 6) + (j << 3) + h]);
    float e[8], sm = 0.f;
#pragma unroll
    for (int j = 0; j < 8; j++) { e[j] = __expf(sc[(i << 6) + (j << 3) + h] - mx); sm += e[j]; }
    float inv = re[i] / sm;
#pragma unroll
    for (int j = 0; j < 8; j++) sc[(i << 6) + (j << 3) + h] = e[j] * inv * se[j];
  }
  __syncthreads();
  for (int idx = t; idx < 4096; idx += 256) {
    int i = idx >> 9, c = idx & 511, h = c >> 6, d = c & 63;
    float s = 0.f;
#pragma unroll
    for (int j = 0; j < 8; j++) s = fmaf(sc[(i << 6) + (j << 3) + h], vs[j * 520 + h * 65 + d], s);
    long oi = ((long)i * 256 + b) * 512 + c;
    float nv = msgsum32[oi] + s;
    msgsum32[oi] = nv;
    msgsum16[oi] = (f16)nv;
  }
}

// ---------------- h = (1-g)*h + g*cand; h fp32 + f16 mirror in cat16 (ld 1024)
__global__ __launch_bounds__(256) void hupdate_kernel(
    float* __restrict__ h32, f16* __restrict__ cat16, const float* __restrict__ gc)
{
  long i4 = ((long)blockIdx.x * 256 + threadIdx.x) * 4; // grid 1024
  long nb = i4 >> 9; int m = (int)(i4 & 511);
  float4 g = *(const float4*)&gc[nb * 1024 + m];
  float4 cd = *(const float4*)&gc[nb * 1024 + 512 + m];
  float4 h = *(const float4*)&h32[i4];
  float4 nh;
  nh.x = (1.f - g.x) * h.x + g.x * cd.x;
  nh.y = (1.f - g.y) * h.y + g.y * cd.y;
  nh.z = (1.f - g.z) * h.z + g.z * cd.z;
  nh.w = (1.f - g.w) * h.w + g.w * cd.w;
  *(float4*)&h32[i4] = nh;
  f16x4 o = {(f16)nh.x, (f16)nh.y, (f16)nh.z, (f16)nh.w};
  *(f16x4*)&cat16[nb * 1024 + m] = o;
}

// ---------------- classifier (fp32)
__global__ __launch_bounds__(256) void cls_kernel(
    const float* __restrict__ h32, const float* __restrict__ wcls,
    const float* __restrict__ bcls, float* __restrict__ out)
{
  __shared__ float As[2][512];
  int n = blockIdx.x >> 7, r0 = (blockIdx.x & 127) * 2;
  int t = threadIdx.x;
  for (int i = t; i < 1024; i += 256)
    As[i >> 9][i & 511] = h32[((long)(n * 256 + r0 + (i >> 9))) * 512 + (i & 511)];
  __syncthreads();
  int r = r0 + (t >> 7), c = t & 127;
  if (c < 100) {
    const float* wp = wcls + (long)n * 512 * 100 + c;
    const float* arow = As[t >> 7];
    float acc = bcls[n * 100 + c];
#pragma unroll 4
    for (int k = 0; k < 512; k++) acc = fmaf(arow[k], wp[k * 100], acc);
    out[((long)(n * 256 + r)) * 100 + c] = acc;
  }
}

extern "C" void kernel_launch(void* const* d_in, const int* in_sizes, int n_in,
                              void* d_out, int out_size, void* d_ws, size_t ws_size,
                              hipStream_t stream)
{
  (void)in_sizes; (void)n_in; (void)out_size;
  const float* x        = (const float*)d_in[0];
  const float* conv1_w  = (const float*)d_in[1];
  const float* conv1_b  = (const float*)d_in[2];
  const float* conv2_w  = (const float*)d_in[3];
  const float* conv2_b  = (const float*)d_in[4];
  const float* feat_w   = (const float*)d_in[5];
  const float* feat_b   = (const float*)d_in[6];
  const float* ctrl_wi  = (const float*)d_in[7];
  const float* ctrl_wh  = (const float*)d_in[8];
  const float* ctrl_bi  = (const float*)d_in[9];
  const float* ctrl_bh  = (const float*)d_in[10];
  const float* send_w   = (const float*)d_in[11];
  const float* send_b   = (const float*)d_in[12];
  const float* recv_w   = (const float*)d_in[13];
  const float* recv_b   = (const float*)d_in[14];
  const float* abias_w  = (const float*)d_in[15];
  const float* abias_b  = (const float*)d_in[16];
  const float* wq       = (const float*)d_in[17];
  const float* wk       = (const float*)d_in[18];
  const float* wv       = (const float*)d_in[19];
  const float* wo       = (const float*)d_in[20];
  const float* bo       = (const float*)d_in[21];
  const float* edge     = (const float*)d_in[22];
  const float* wr       = (const float*)d_in[23];
  const float* br       = (const float*)d_in[24];
  const float* wg       = (const float*)d_in[25];
  const float* bg       = (const float*)d_in[26];
  const float* wc       = (const float*)d_in[27];
  const float* bc       = (const float*)d_in[28];
  const float* wcls     = (const float*)d_in[29];
  const float* bcls     = (const float*)d_in[30];

  // ---- workspace layout (f32 then f16)
  float* f32b = (float*)d_ws;
  float* h32      = f32b;             // 1,048,576
  float* qkvb     = f32b + 1048576;   // 3,538,944
  float* gc       = f32b + 4587520;   // 2,097,152
  float* msgsum32 = f32b + 6684672;   // 1,048,576
  float* cs       = f32b + 7733248;   // 131,072
  float* sendb    = f32b + 7864320;   // 2,048
  float* recvb    = f32b + 7866368;   // 2,048
  float* abb      = f32b + 7868416;   // 16,384
  float* bor32    = f32b + 7884800;   // 4,096
  float* bgr      = f32b + 7888896;   // 4,096
  float* vg2b     = f32b + 7892992;   // 4,096
  float* bcr      = f32b + 7897088;   // 4,096
  float* vc2b     = f32b + 7901184;   // 4,096
  f16* hb = (f16*)(f32b + 7905280);
  f16* pooled16 = hb;                 // 262,144
  f16* cat16    = hb + 262144;        // 2,097,152  [h|feats] ld 1024
  f16* msgsum16 = hb + 2359296;       // 1,048,576
  f16* wqT      = hb + 3407872;       // 2,097,152  (wk,wv,wi contiguous after)
  f16* wiT      = hb + 9699328;       // 786,432
  f16* featwT   = hb + 10485760;      // 524,288
  f16* wrT      = hb + 11010048;      // 2,097,152 (x0.125)
  f16* wgT      = hb + 13107200;      // 6,291,456 (wcT contiguous after)
  f16* wcT      = hb + 19398656;      // 6,291,456
  f16* c2wp     = hb + 25690112;      // 589,824
  f16* wo16     = hb + 26279936;      // 2,097,152
  f16* P        = hb + 28377088;      // 2,097,152  (wo@wr)/8 [c][m]
  f16* P2       = hb + 30474240;      // 2,097,152  duplicate of P
  f16* WeffGT   = hb + 32571392;      // 2,097,152  (WeffCT contiguous after)
  f16* WeffCT   = hb + 34668544;      // 2,097,152
  f16* w1p      = hb + 36765696;      // 16,384
  // total bytes = 31,621,120 + 73,564,160 = 105,185,280
  if (ws_size < 105185280ull) return;

  hipMemsetAsync(cs, 0, 131072 * 4, stream);
  hipMemsetAsync(msgsum32, 0, 1048576 * 4, stream);

  // ---- one-time weight prep
  twmulti4_kernel<<<dim3(8, 8, 32), 256, 0, stream>>>(wq, wk, wv, ctrl_wi, wqT);
  twmulti2_kernel<<<dim3(8, 24, 16), 256, 0, stream>>>(wg, wc, wgT);
  tw64_kernel<<<dim3(8, 8, 8), 256, 0, stream>>>(wr, wrT, 512, 512, 0.125f);
  tw64_kernel<<<dim3(8, 2, 8), 256, 0, stream>>>(feat_w, featwT, 128, 512, 1.f);
  cconv_kernel<<<1024, 256, 0, stream>>>(wo, wo16);
  c2wconv_kernel<<<2304, 256, 0, stream>>>(conv2_w, c2wp);
  w1prep_kernel<<<64, 256, 0, stream>>>(conv1_w, w1p);
  bor_kernel<<<dim3(2, 8), 256, 0, stream>>>(bo, wr, bor32);
  biasfold_kernel<<<dim3(2, 8), 256, 0, stream>>>(wg, wc, bg, bc, br, bor32,
                                                  bgr, vg2b, bcr, vc2b);
  // P[c][m] = sum_d wo[c][d] * (wr[d][m]/8)   (mirrored into P2)
  {
    SegsM s{};
    s.BT[0] = wrT; s.sBT[0] = 262144;
    gemmf16_kernel<<<dim3(8, 8, 8), 256, 0, stream>>>(
        wo16, 262144L, 512, nullptr, 0L, 0, 1 << 20,
        s, 512, 512, 0, 0.f,
        nullptr, 0L, 0, P, P2, 262144L, 512);
  }
  // Weff{G,C}T[o][c] = sum_m wgT/wcT[o][1024+m] * P[c][m]   (z=16 batched)
  {
    SegsM s{};
    s.BT[0] = P; s.sBT[0] = 262144;
    gemmf16_kernel<<<dim3(8, 8, 16), 256, 0, stream>>>(
        wgT + 1024, 786432L, 1536, nullptr, 0L, 0, 1 << 20,
        s, 512, 512, 0, 0.f,
        nullptr, 0L, 0, WeffGT, nullptr, 262144L, 512);
  }

  // ---- fused feature extraction -> pooled16
  convfused_kernel<<<dim3(256, 8), 256, 0, stream>>>(x, w1p, conv1_b, c2wp, conv2_b, pooled16);

  // feats = relu(pooled @ feat_w + b) -> cat16[512:1024]; h-init -> h32 + cat16[0:512]
  {
    SegsM s{};
    s.BT[0] = featwT; s.sBT[0] = 65536; s.bias[0] = feat_b; s.sBias[0] = 512; s.act[0] = 1;
    gemmf16_kernel<<<dim3(8, 4, 8), 256, 0, stream>>>(
        pooled16, 32768L, 128, nullptr, 0L, 0, 1 << 20,
        s, 128, 128, 0, 0.f,
        h32, 131072L, 512, cat16 + 512, cat16, 262144L, 1024);
  }

  for (int step = 0; step < 3; step++) {
    // q|k|v|gi = h @ {wq,wk,wv,ctrl_wi}
    {
      SegsM s{};
      s.BT[0] = wqT; s.BT[1] = wqT + 2097152; s.BT[2] = wqT + 4194304; s.BT[3] = wiT;
      s.sBT[0] = 262144; s.sBT[1] = 262144; s.sBT[2] = 262144; s.sBT[3] = 98304;
      s.bias[3] = ctrl_bi; s.sBias[3] = 192;
      gemmf16_kernel<<<dim3(27, 4, 8), 256, 0, stream>>>(
          cat16, 262144L, 1024, nullptr, 0L, 0, 1 << 20,
          s, 512, 512, 0, 0.f,
          qkvb, 442368L, 1728, nullptr, nullptr, 0L, 0);
    }
    gru_kernel<<<dim3(256, 8), 64, 0, stream>>>(
        qkvb, ctrl_wh, ctrl_bh, cs, send_w, send_b, recv_w, recv_b,
        abias_w, abias_b, sendb, recvb, abb);
    attn_kernel<<<256, 256, 0, stream>>>(qkvb, edge, sendb, recvb, abb, msgsum32, msgsum16);
    // g|cand = act( [h|feats] @ Wg/c_hf  +  msgsum @ Weff  + bias + (t+1)*bias2 )
    {
      SegsM s{};
      s.BT[0] = wgT; s.BT[1] = wcT;
      s.sBT[0] = 786432; s.sBT[1] = 786432;
      s.BT2[0] = WeffGT; s.BT2[1] = WeffCT;
      s.sBT2[0] = 262144; s.sBT2[1] = 262144;
      s.bias[0] = bgr; s.bias[1] = bcr; s.sBias[0] = 512; s.sBias[1] = 512;
      s.bias2[0] = vg2b; s.bias2[1] = vc2b; s.sBias2[0] = 512; s.sBias2[1] = 512;
      s.act[0] = 2; s.act[1] = 3;
      gemmf16_kernel<<<dim3(16, 4, 8), 256, 0, stream>>>(
          cat16, 262144L, 1024, msgsum16, 131072L, 512, 16,
          s, 1536, 1536, 512, (float)(step + 1),
          gc, 262144L, 1024, nullptr, nullptr, 0L, 0);
    }
    hupdate_kernel<<<1024, 256, 0, stream>>>(h32, cat16, gc);
  }
  cls_kernel<<<1024, 256, 0, stream>>>(h32, wcls, bcls, (float*)d_out);
}

// Round 5
// 393.295 us; speedup vs baseline: 4.3881x; 1.0437x over previous
//
#include <hip/hip_runtime.h>
#include <hip/hip_bf16.h>

// DNBN system, f16-MFMA, round 5.
// N=8, B=256, M=512, C=512, NH=8, DH=64, S=8, HC=64, T=3, OUT=100.
// T(3) < S(8) -> FIFO never evicts -> buf.mean == msum/8.
// Round 5: convfused slimmed to 53.6KB LDS (3 blocks/CU); gru+attn fused into
// step_kernel; hupdate fused into gatefused GEMM epilogue (double-buffered h16);
// biascombo prep with transposed f16 reads; q/k/v stored f16; memsets removed.

typedef _Float16 f16;
typedef _Float16 f16x8 __attribute__((ext_vector_type(8)));
typedef _Float16 f16x4 __attribute__((ext_vector_type(4)));
typedef float f32x4 __attribute__((ext_vector_type(4)));

#define GLOAD_LDS16(gsrc, ldst)                                                   \
  __builtin_amdgcn_global_load_lds(                                               \
      (const __attribute__((address_space(1))) void*)(gsrc),                      \
      (__attribute__((address_space(3))) void*)(ldst), 16, 0, 0)

// ---------------- transpose+convert tile body: [K][N] f32 -> [N][K] f16 (scaled)
__device__ __forceinline__ void tw64_body(
    const float* __restrict__ s, f16* __restrict__ d, int K, int N, float scale,
    int n0, int k0, int t)
{
  __shared__ float tile[64][65];
#pragma unroll
  for (int p = 0; p < 4; p++) {
    int idx = t + p * 256;
    int kk = idx >> 4, nq = (idx & 15) * 4;
    float4 v = *(const float4*)&s[(long)(k0 + kk) * N + n0 + nq];
    tile[kk][nq] = v.x; tile[kk][nq + 1] = v.y; tile[kk][nq + 2] = v.z; tile[kk][nq + 3] = v.w;
  }
  __syncthreads();
#pragma unroll
  for (int p = 0; p < 2; p++) {
    int idx = t + p * 256;
    int nn = idx >> 3, kc = (idx & 7) * 8;
    f16 o[8];
#pragma unroll
    for (int i = 0; i < 8; i++) o[i] = (f16)(tile[kc + i][nn] * scale);
    *(f16x8*)&d[(long)(n0 + nn) * K + k0 + kc] = *(const f16x8*)o;
  }
}

__global__ __launch_bounds__(256) void tw64_kernel(
    const float* __restrict__ src, f16* __restrict__ dst, int K, int N, float scale)
{
  int z = blockIdx.z;
  tw64_body(src + (long)z * K * N, dst + (long)z * N * K, K, N, scale,
            blockIdx.x * 64, blockIdx.y * 64, threadIdx.x);
}

// wq|wk|wv|wi batched transpose: z = sel*8 + e
__global__ __launch_bounds__(256) void twmulti4_kernel(
    const float* __restrict__ wq, const float* __restrict__ wk,
    const float* __restrict__ wv, const float* __restrict__ wi, f16* __restrict__ wqT)
{
  int z = blockIdx.z, sel = z >> 3, e = z & 7;
  int N = (sel < 3) ? 512 : 192;
  int n0 = blockIdx.x * 64;
  if (n0 >= N) return;
  const float* src = (sel == 0) ? wq : (sel == 1) ? wk : (sel == 2) ? wv : wi;
  f16* dst = (sel < 3) ? (wqT + (long)sel * 2097152 + (long)e * 262144)
                       : (wqT + 3L * 2097152 + (long)e * 98304);
  tw64_body(src + (long)e * 512 * N, dst, 512, N, 1.f, n0, blockIdx.y * 64, threadIdx.x);
}

// wg|wc batched transpose: z = sel*8 + e
__global__ __launch_bounds__(256) void twmulti2_kernel(
    const float* __restrict__ wg, const float* __restrict__ wc, f16* __restrict__ wgT)
{
  int z = blockIdx.z, sel = z >> 3, e = z & 7;
  const float* src = sel ? wc : wg;
  f16* dst = wgT + (long)sel * 6291456 + (long)e * 786432;
  tw64_body(src + (long)e * 1536 * 512, dst, 1536, 512, 1.f,
            blockIdx.x * 64, blockIdx.y * 64, threadIdx.x);
}

// ---------------- merged small preps: wo->f16, conv2-w permute, conv1-w prep
__global__ __launch_bounds__(256) void smallprep_kernel(
    const float* __restrict__ wo, f16* __restrict__ wo16,
    const float* __restrict__ c2src, f16* __restrict__ c2dst,
    const float* __restrict__ w1src, f16* __restrict__ w1dst)
{
  int bid = blockIdx.x, t = threadIdx.x;
  if (bid < 1024) {
    long i = ((long)bid * 256 + t) * 8;
    float4 a = *(const float4*)&wo[i];
    float4 b = *(const float4*)&wo[i + 4];
    f16 o[8] = {(f16)a.x, (f16)a.y, (f16)a.z, (f16)a.w, (f16)b.x, (f16)b.y, (f16)b.z, (f16)b.w};
    *(f16x8*)&wo16[i] = *(const f16x8*)o;
  } else if (bid < 3328) {
    long i = (long)(bid - 1024) * 256 + t; // 589824
    int ci = i & 63; long r = i >> 6; int tap = r % 9; r /= 9; int co = r & 127; int n = (int)(r >> 7);
    c2dst[i] = (f16)c2src[(((long)(n * 128 + co) * 64 + ci) * 9) + tap];
  } else {
    int i = (bid - 3328) * 256 + t; // 16384
    int j = i & 7, co = (i >> 3) & 63, slot = (i >> 9) & 3, e = i >> 11;
    int k = slot * 8 + j;
    w1dst[i] = (f16)((k < 27) ? w1src[(long)e * 1728 + co * 27 + k] : 0.f);
  }
}

// ---------------- bias prep: bor = bo@wr/8; bgr/vg2/bcr/vc2 folds (f16 rows)
__global__ __launch_bounds__(512) void biascombo_kernel(
    const f16* __restrict__ wrT, const float* __restrict__ bo,
    const f16* __restrict__ wgT, const f16* __restrict__ wcT,
    const float* __restrict__ br, const float* __restrict__ bg, const float* __restrict__ bc,
    float* __restrict__ bor32, float* __restrict__ bgr, float* __restrict__ vg2,
    float* __restrict__ bcr, float* __restrict__ vc2)
{
  int n = blockIdx.x, t = threadIdx.x;
  __shared__ float bosh[512], brsh[512], borsh[512];
  bosh[t] = bo[n * 512 + t];
  brsh[t] = br[n * 512 + t];
  __syncthreads();
  {
    const f16* wrow = wrT + (long)n * 262144 + (long)t * 512; // x0.125 folded
    float s = 0.f;
    for (int c = 0; c < 512; c += 8) {
      f16x8 v = *(const f16x8*)&wrow[c];
#pragma unroll
      for (int q = 0; q < 8; q++) s = fmaf((float)v[q], bosh[c + q], s);
    }
    bor32[n * 512 + t] = s;
    borsh[t] = s;
  }
  __syncthreads();
  const f16* gr = wgT + (long)n * 786432 + (long)t * 1536 + 1024;
  const f16* cr = wcT + (long)n * 786432 + (long)t * 1536 + 1024;
  float s1g = 0.f, s2g = 0.f, s1c = 0.f, s2c = 0.f;
  for (int m = 0; m < 512; m += 8) {
    f16x8 vg = *(const f16x8*)&gr[m];
    f16x8 vc = *(const f16x8*)&cr[m];
#pragma unroll
    for (int q = 0; q < 8; q++) {
      float brm = brsh[m + q], borm = borsh[m + q];
      s1g = fmaf(brm, (float)vg[q], s1g); s2g = fmaf(borm, (float)vg[q], s2g);
      s1c = fmaf(brm, (float)vc[q], s1c); s2c = fmaf(borm, (float)vc[q], s2c);
    }
  }
  bgr[n * 512 + t] = bg[n * 512 + t] + s1g; vg2[n * 512 + t] = s2g;
  bcr[n * 512 + t] = bc[n * 512 + t] + s1c; vc2[n * 512 + t] = s2c;
}

// ---------------- fused conv1(MFMA)+conv2(MFMA)+pool: one block per (b,e)
// LDS 53,632 B -> 3 blocks/CU.
__global__ __launch_bounds__(256) void convfused_kernel(
    const float* __restrict__ x, const f16* __restrict__ w1p, const float* __restrict__ b1,
    const f16* __restrict__ w2p, const float* __restrict__ b2, f16* __restrict__ pooled16)
{
  __shared__ __align__(16) char lds[53632];
  // region0 [0,16384): xpatch (ph1-2) / Asub single-buf (ph3) / red (final)
  f16* xpatch = (f16*)lds;
  f16* AsubS = (f16*)lds;
  float* red = (float*)lds;
  float* bs1 = (float*)(lds + 16384);          // 256B, conv1 bias
  f16* h1s = (f16*)(lds + 16640);              // 36,992B [289 pix][64 ci] swizzled
  float* xs = (float*)(lds + 16640);           // 12KB alias (ph0-1)
  f16* ws1 = (f16*)(lds + 16640 + 12288);      // 4KB alias (ph0-2)

  int b = blockIdx.x, e = blockIdx.y;
  int t = threadIdx.x, w = t >> 6, l = t & 63;

  // phase 0: stage x[b] (12KB), w1p[e] (4KB), b1
  const float* xb = x + (long)b * 3072;
#pragma unroll
  for (int c0 = 0; c0 < 3; c0++) {
    int c = w * 3 + c0;
    GLOAD_LDS16(xb + c * 256 + l * 4, (char*)xs + c * 1024);
  }
  GLOAD_LDS16(w1p + (long)e * 2048 + w * 512 + l * 8, (char*)ws1 + w * 1024);
  if (t < 64) bs1[t] = b1[e * 64 + t];
  asm volatile("s_waitcnt vmcnt(0)" ::: "memory");
  __syncthreads();

  // phase 1: im2col patch; thread t = output pixel (oy,ox)
  {
    int oy = t >> 4, ox = t & 15;
    f16 pv[32];
#pragma unroll
    for (int q = 27; q < 32; q++) pv[q] = (f16)0.f;
#pragma unroll
    for (int ci = 0; ci < 3; ci++)
#pragma unroll
      for (int ky = 0; ky < 3; ky++) {
        int iy = oy * 2 + ky;
#pragma unroll
        for (int kx = 0; kx < 3; kx++) {
          int ix = ox * 2 + kx;
          pv[ci * 9 + ky * 3 + kx] =
              (f16)((iy < 32 && ix < 32) ? xs[ci * 1024 + iy * 32 + ix] : 0.f);
        }
      }
#pragma unroll
    for (int c = 0; c < 4; c++) *(f16x8*)&xpatch[c * 2048 + t * 8] = *(const f16x8*)&pv[c * 8];
  }
  __syncthreads();

  // phase 2: conv1 MFMA; wave w owns pixels w*64..+63
  {
    int pw = w * 64;
    f16x8 a1[4], b1f[4];
#pragma unroll
    for (int i = 0; i < 4; i++)
      a1[i] = *(const f16x8*)&ws1[(l >> 4) * 512 + (i * 16 + (l & 15)) * 8];
#pragma unroll
    for (int jj = 0; jj < 4; jj++)
      b1f[jj] = *(const f16x8*)&xpatch[(l >> 4) * 2048 + (pw + jj * 16 + (l & 15)) * 8];
    __syncthreads(); // all frag loads done before h1s epilogue overwrites xs/ws1 aliases
    f32x4 acc1[4][4];
#pragma unroll
    for (int i = 0; i < 4; i++)
#pragma unroll
      for (int jj = 0; jj < 4; jj++)
        acc1[i][jj] = __builtin_amdgcn_mfma_f32_16x16x32_f16(
            a1[i], b1f[jj], (f32x4){0.f, 0.f, 0.f, 0.f}, 0, 0, 0);
#pragma unroll
    for (int i = 0; i < 4; i++) {
      int co0 = i * 16 + ((l >> 4) << 2);
      float bi0 = bs1[co0], bi1 = bs1[co0 + 1], bi2 = bs1[co0 + 2], bi3 = bs1[co0 + 3];
#pragma unroll
      for (int jj = 0; jj < 4; jj++) {
        int p2 = pw + jj * 16 + (l & 15);
        int oy2 = p2 >> 4, ox2 = p2 & 15;
        int p = oy2 * 17 + ox2;
        int fs = ((ox2 >> 1) + oy2) & 7;
        int slot = (co0 >> 3) ^ fs;
        f16x4 v;
        v[0] = (f16)fmaxf(acc1[i][jj][0] + bi0, 0.f);
        v[1] = (f16)fmaxf(acc1[i][jj][1] + bi1, 0.f);
        v[2] = (f16)fmaxf(acc1[i][jj][2] + bi2, 0.f);
        v[3] = (f16)fmaxf(acc1[i][jj][3] + bi3, 0.f);
        *(f16x4*)&h1s[p * 64 + slot * 8 + (co0 & 7)] = v;
      }
    }
  }
  if (t < 33) { // zero guard ring (row 16 + col 16)
    int gy = (t < 17) ? 16 : (t - 17);
    int gx = (t < 17) ? t : 16;
    int p = gy * 17 + gx;
    f16x8 zz = {};
#pragma unroll
    for (int g = 0; g < 8; g++) *(f16x8*)&h1s[p * 64 + g * 8] = zz;
  }

  // phase 3: conv2 MFMA over 9 taps, single-buffer A, 3 blocks/CU hides stalls
  int waveR = w >> 1, waveC = w & 1;
  const f16* wbase = w2p + (long)e * 73728;
  f32x4 acc[4][2];
#pragma unroll
  for (int i = 0; i < 4; i++) {
    acc[i][0] = (f32x4){0.f, 0.f, 0.f, 0.f};
    acc[i][1] = (f32x4){0.f, 0.f, 0.f, 0.f};
  }
  for (int tap = 0; tap < 9; tap++) {
    __syncthreads(); // prev-tap frag reads done (tap0: h1s/guard writes done)
#pragma unroll
    for (int c = 0; c < 4; c++) {
      int ch = w * 4 + c;
      int co = ch * 8 + (l >> 3);
      int g = (l & 7) ^ (co & 7);
      GLOAD_LDS16(wbase + ((long)co * 9 + tap) * 64 + g * 8, &AsubS[ch * 512]);
    }
    asm volatile("s_waitcnt vmcnt(0)" ::: "memory");
    __syncthreads();
    int ky = tap / 3, kx = tap - ky * 3;
#pragma unroll
    for (int kk = 0; kk < 2; kk++) {
      f16x8 af[4], bf[2];
#pragma unroll
      for (int i = 0; i < 4; i++) {
        int row = waveR * 64 + i * 16 + (l & 15);
        int blk = (kk * 4 + (l >> 4)) ^ (row & 7);
        af[i] = *(const f16x8*)&AsubS[row * 64 + blk * 8];
      }
#pragma unroll
      for (int j = 0; j < 2; j++) {
        int sp = waveC * 32 + j * 16 + (l & 15);
        int iy = (sp >> 3) * 2 + ky, ix = (sp & 7) * 2 + kx;
        int fs = ((ix >> 1) + iy) & 7;
        int blk = (kk * 4 + (l >> 4)) ^ fs;
        bf[j] = *(const f16x8*)&h1s[(iy * 17 + ix) * 64 + blk * 8];
      }
#pragma unroll
      for (int i = 0; i < 4; i++)
#pragma unroll
        for (int j = 0; j < 2; j++)
          acc[i][j] = __builtin_amdgcn_mfma_f32_16x16x32_f16(af[i], bf[j], acc[i][j], 0, 0, 0);
    }
  }
  // epilogue: relu(acc+bias) summed over 64 spatial cols, /64
  __syncthreads(); // AsubS dead -> red
  const float* bn2 = b2 + e * 128;
#pragma unroll
  for (int i = 0; i < 4; i++) {
#pragma unroll
    for (int reg = 0; reg < 4; reg++) {
      int row = waveR * 64 + i * 16 + ((l >> 4) << 2) + reg;
      float bi = bn2[row];
      float s = fmaxf(acc[i][0][reg] + bi, 0.f) + fmaxf(acc[i][1][reg] + bi, 0.f);
      s += __shfl_xor(s, 1); s += __shfl_xor(s, 2);
      s += __shfl_xor(s, 4); s += __shfl_xor(s, 8);
      if ((l & 15) == 0) red[waveC * 128 + row] = s;
    }
  }
  __syncthreads();
  if (t < 128) {
    float v = (red[t] + red[128 + t]) * (1.f / 64.f);
    pooled16[((long)e * 256 + b) * 128 + t] = (f16)v;
  }
}

// ---------------- generic segmented f16-MFMA GEMM: 64x64 tile, per-seg outputs
struct SegsM {
  const f16* BT[4];
  const float* bias[4];
  f16* o16[4];
  f16* o16b[4];
  float* o32[4];
  long sBT[4], sBias[4], sO16[4], sO32[4];
  int ldo16[4], ldo32[4], act[4];
};

__global__ __launch_bounds__(256) void gemmf16_kernel(
    const f16* __restrict__ A, long sA, int lda, SegsM segs, int K)
{
  __shared__ __align__(16) f16 Asub[2][4096];
  __shared__ __align__(16) f16 Bsub[2][4096];
  int z = blockIdx.z;
  int rowBase = blockIdx.y * 64;
  int vcBase = blockIdx.x * 64;
  int seg = vcBase >> 9;
  int lcBase = vcBase & 511;
  const f16* An = A + (long)z * sA + (long)rowBase * lda;
  const f16* BTn = segs.BT[seg] + (long)z * segs.sBT[seg] + (long)lcBase * K;
  const float* biasN = segs.bias[seg] ? segs.bias[seg] + (long)z * segs.sBias[seg] : nullptr;
  int act = segs.act[seg];
  int t = threadIdx.x, w = t >> 6, l = t & 63;
  int waveR = w >> 1, waveC = w & 1;
  f32x4 acc[2][2];
#pragma unroll
  for (int i = 0; i < 2; i++) {
    acc[i][0] = (f32x4){0.f, 0.f, 0.f, 0.f};
    acc[i][1] = (f32x4){0.f, 0.f, 0.f, 0.f};
  }
  auto stage = [&](int buf, int kt) {
    int k0 = kt << 6;
#pragma unroll
    for (int c = 0; c < 2; c++) {
      int ch = w * 2 + c;
      int row = ch * 8 + (l >> 3);
      int g = (l & 7) ^ (row & 7);
      GLOAD_LDS16(An + (long)row * lda + k0 + g * 8, &Asub[buf][ch * 512]);
    }
#pragma unroll
    for (int c = 0; c < 2; c++) {
      int ch = w * 2 + c;
      int col = ch * 8 + (l >> 3);
      int g = (l & 7) ^ (col & 7);
      GLOAD_LDS16(BTn + (long)col * K + k0 + g * 8, &Bsub[buf][ch * 512]);
    }
  };
  int nk = K >> 6;
  stage(0, 0);
  asm volatile("s_waitcnt vmcnt(0)" ::: "memory");
  __syncthreads();
  int cur = 0;
  for (int kt = 0; kt < nk; kt++) {
    if (kt + 1 < nk) stage(cur ^ 1, kt + 1);
#pragma unroll
    for (int kk = 0; kk < 2; kk++) {
      f16x8 af[2], bf[2];
#pragma unroll
      for (int i = 0; i < 2; i++) {
        int row = waveR * 32 + i * 16 + (l & 15);
        int blk = (kk * 4 + (l >> 4)) ^ (row & 7);
        af[i] = *(const f16x8*)&Asub[cur][row * 64 + blk * 8];
      }
#pragma unroll
      for (int j = 0; j < 2; j++) {
        int col = waveC * 32 + j * 16 + (l & 15);
        int blk = (kk * 4 + (l >> 4)) ^ (col & 7);
        bf[j] = *(const f16x8*)&Bsub[cur][col * 64 + blk * 8];
      }
#pragma unroll
      for (int i = 0; i < 2; i++)
#pragma unroll
        for (int j = 0; j < 2; j++)
          acc[i][j] = __builtin_amdgcn_mfma_f32_16x16x32_f16(af[i], bf[j], acc[i][j], 0, 0, 0);
    }
    if (kt + 1 < nk) {
      asm volatile("s_waitcnt vmcnt(0)" ::: "memory");
      __syncthreads();
      cur ^= 1;
    }
  }
  f16* o16 = segs.o16[seg];
  f16* o16b = segs.o16b[seg];
  float* o32 = segs.o32[seg];
  long sO16 = segs.sO16[seg], sO32 = segs.sO32[seg];
  int ldo16 = segs.ldo16[seg], ldo32 = segs.ldo32[seg];
#pragma unroll
  for (int i = 0; i < 2; i++) {
    int rb = rowBase + waveR * 32 + i * 16 + ((l >> 4) << 2);
#pragma unroll
    for (int j = 0; j < 2; j++) {
      int lc = lcBase + waveC * 32 + j * 16 + (l & 15);
      float bv = biasN ? biasN[lc] : 0.f;
#pragma unroll
      for (int reg = 0; reg < 4; reg++) {
        float v = acc[i][j][reg] + bv;
        if (act == 1) v = fmaxf(v, 0.f);
        else if (act == 2) v = 1.f / (1.f + __expf(-v));
        else if (act == 3) v = tanhf(v);
        long rr = rb + reg;
        if (o16) o16[(long)z * sO16 + rr * ldo16 + lc] = (f16)v;
        if (o16b) o16b[(long)z * sO16 + rr * ldo16 + lc] = (f16)v;
        if (o32) o32[(long)z * sO32 + rr * ldo32 + lc] = v;
      }
    }
  }
}

// ---------------- per-step fused GRU + gates + 8-node attention
__global__ __launch_bounds__(256) void step_kernel(
    const f16* __restrict__ qkv16, const float* __restrict__ gi32,
    const float* __restrict__ wh, const float* __restrict__ bh,
    float* __restrict__ cs, const float* __restrict__ sw, const float* __restrict__ sb,
    const float* __restrict__ rw, const float* __restrict__ rb,
    const float* __restrict__ aw, const float* __restrict__ abb,
    const float* __restrict__ edge,
    float* __restrict__ msgsum32, f16* __restrict__ msgsum16, int step)
{
  int b = blockIdx.x, t = threadIdx.x;
  __shared__ float qs[8 * 520], ks[8 * 520];
  __shared__ f16 vs16[8 * 520];
  __shared__ float csh[512];
  __shared__ float sc[512];
  __shared__ float se[8], re[8], edg[64], abl[64];

  // stage q/k/v (f16 -> f32 for q,k; f16 for v)
  for (int i = t; i < 4096; i += 256) {
    int nn = i >> 9, c = i & 511, h = c >> 6, d = c & 63;
    long base = ((long)nn * 256 + b) * 1536 + c;
    int la = nn * 520 + h * 65 + d;
    qs[la] = (float)qkv16[base];
    ks[la] = (float)qkv16[base + 512];
    vs16[la] = qkv16[base + 1024];
  }
  if (t >= 192) edg[t - 192] = edge[t - 192];
  int n0 = t >> 6, hc = t & 63;
  if (step > 0) {
    csh[t] = cs[((long)n0 * 256 + b) * 64 + hc];
    csh[t + 256] = cs[((long)(n0 + 4) * 256 + b) * 64 + hc];
  }
  __syncthreads();

  // GRU for (n0,hc) and (n0+4,hc)
  float cn[2];
#pragma unroll
  for (int u = 0; u < 2; u++) {
    int n = n0 + u * 4;
    long nb = (long)n * 256 + b;
    float c0 = (step > 0) ? csh[n * 64 + hc] : 0.f;
    float g0 = bh[n * 192 + hc], g1 = bh[n * 192 + 64 + hc], g2 = bh[n * 192 + 128 + hc];
    if (step > 0) {
      const float* whn = wh + (long)n * 12288;
      for (int k = 0; k < 64; k++) {
        float cv = csh[n * 64 + k];
        g0 = fmaf(cv, whn[k * 192 + hc], g0);
        g1 = fmaf(cv, whn[k * 192 + 64 + hc], g1);
        g2 = fmaf(cv, whn[k * 192 + 128 + hc], g2);
      }
    }
    const float* gi = gi32 + nb * 192;
    float zg = 1.f / (1.f + __expf(-(gi[hc] + g0)));
    float rg = 1.f / (1.f + __expf(-(gi[64 + hc] + g1)));
    float ng = tanhf(gi[128 + hc] + rg * g2);
    cn[u] = (1.f - zg) * ng + zg * c0;
    cs[nb * 64 + hc] = cn[u];
  }
  // gates via wave-wide reductions (wave = one n0)
#pragma unroll
  for (int u = 0; u < 2; u++) {
    int n = n0 + u * 4;
    float ps = cn[u] * sw[n * 64 + hc];
    float pr = cn[u] * rw[n * 64 + hc];
#pragma unroll
    for (int o = 32; o; o >>= 1) { ps += __shfl_xor(ps, o); pr += __shfl_xor(pr, o); }
    if (hc == 0) {
      se[n] = 1.f / (1.f + __expf(-(ps + sb[n])));
      re[n] = 1.f / (1.f + __expf(-(pr + rb[n])));
    }
#pragma unroll
    for (int kk = 0; kk < 8; kk++) {
      float pa = cn[u] * aw[(n * 64 + hc) * 8 + kk];
#pragma unroll
      for (int o = 32; o; o >>= 1) pa += __shfl_xor(pa, o);
      if (hc == 0) abl[n * 8 + kk] = pa + abb[n * 8 + kk];
    }
  }
  __syncthreads();

  // scores [i][j][h]
  for (int idx = t; idx < 512; idx += 256) {
    int i = idx >> 6, j = (idx >> 3) & 7, h = idx & 7;
    const float* qp = &qs[i * 520 + h * 65];
    const float* kp = &ks[j * 520 + h * 65];
    float s = 0.f;
#pragma unroll
    for (int d = 0; d < 64; d++) s = fmaf(qp[d], kp[d], s);
    sc[idx] = s * 0.125f + edg[i * 8 + j] + abl[i * 8 + h];
  }
  __syncthreads();
  if (t < 64) {
    int i = t >> 3, h = t & 7;
    float mx = -1e30f;
#pragma unroll
    for (int j = 0; j < 8; j++) mx = fmaxf(mx, sc[(i << 6) + (j << 3) + h]);
    float e[8], sm = 0.f;
#pragma unroll
    for (int j = 0; j < 8; j++) { e[j] = __expf(sc[(i << 6) + (j << 3) + h] - mx); sm += e[j]; }
    float inv = re[i] / sm;
#pragma unroll
    for (int j = 0; j < 8; j++) sc[(i << 6) + (j << 3) + h] = e[j] * inv * se[j];
  }
  __syncthreads();
  // PV + msgsum accumulate
  for (int idx = t; idx < 4096; idx += 256) {
    int i = idx >> 9, c = idx & 511, h = c >> 6, d = c & 63;
    float s = 0.f;
#pragma unroll
    for (int j = 0; j < 8; j++)
      s = fmaf(sc[(i << 6) + (j << 3) + h], (float)vs16[j * 520 + h * 65 + d], s);
    long oi = ((long)i * 256 + b) * 512 + c;
    float nv = (step == 0) ? s : (msgsum32[oi] + s);
    msgsum32[oi] = nv;
    msgsum16[oi] = (f16)nv;
  }
}

// ---------------- fused gate GEMM + h-update:
// g|cand = act( h@Wg_h + feats@Wg_f + msgsum@WeffG + bgr + tp1*vg2 ), then
// h_new = (1-g)*h + g*cand -> h32 + h16next
__global__ __launch_bounds__(256) void gatefused_kernel(
    const f16* __restrict__ h16cur, const f16* __restrict__ feats16,
    const f16* __restrict__ msgsum16,
    const f16* __restrict__ wgT, const f16* __restrict__ wcT,
    const f16* __restrict__ WeffGT, const f16* __restrict__ WeffCT,
    const float* __restrict__ bgr, const float* __restrict__ vg2,
    const float* __restrict__ bcr, const float* __restrict__ vc2,
    float* __restrict__ h32, f16* __restrict__ h16next, float tp1)
{
  __shared__ __align__(16) f16 Asub[2][2048];
  __shared__ __align__(16) f16 Bgs[2][4096];
  __shared__ __align__(16) f16 Bcs[2][4096];
  int z = blockIdx.z;
  int rowBase = blockIdx.y * 32;   // batch rows
  int colBase = blockIdx.x * 64;   // m cols
  int t = threadIdx.x, w = t >> 6, l = t & 63;
  int waveR = w >> 1, waveC = w & 1;
  f32x4 accG[2], accC[2];
  accG[0] = (f32x4){0.f, 0.f, 0.f, 0.f}; accG[1] = accG[0];
  accC[0] = accG[0]; accC[1] = accG[0];

  auto stage = [&](int buf, int kt) {
    // A
    {
      const f16* asrc;
      if (kt < 8)       asrc = h16cur  + (long)z * 131072 + kt * 64;
      else if (kt < 16) asrc = feats16 + (long)z * 131072 + (kt - 8) * 64;
      else              asrc = msgsum16 + (long)z * 131072 + (kt - 16) * 64;
      int row = w * 8 + (l >> 3);
      int g = (l & 7) ^ (row & 7);
      GLOAD_LDS16(asrc + (long)(rowBase + row) * 512 + g * 8, &Asub[buf][w * 512]);
    }
    // Bg / Bc
#pragma unroll
    for (int c = 0; c < 2; c++) {
      int ch = w * 2 + c;
      int cl = ch * 8 + (l >> 3);
      int g = (l & 7) ^ (cl & 7);
      const f16 *bgsrc, *bcsrc;
      if (kt < 16) {
        bgsrc = wgT + (long)z * 786432 + (long)(colBase + cl) * 1536 + kt * 64 + g * 8;
        bcsrc = wcT + (long)z * 786432 + (long)(colBase + cl) * 1536 + kt * 64 + g * 8;
      } else {
        bgsrc = WeffGT + (long)z * 262144 + (long)(colBase + cl) * 512 + (kt - 16) * 64 + g * 8;
        bcsrc = WeffCT + (long)z * 262144 + (long)(colBase + cl) * 512 + (kt - 16) * 64 + g * 8;
      }
      GLOAD_LDS16(bgsrc, &Bgs[buf][ch * 512]);
      GLOAD_LDS16(bcsrc, &Bcs[buf][ch * 512]);
    }
  };
  stage(0, 0);
  asm volatile("s_waitcnt vmcnt(0)" ::: "memory");
  __syncthreads();
  int cur = 0;
  for (int kt = 0; kt < 24; kt++) {
    if (kt + 1 < 24) stage(cur ^ 1, kt + 1);
#pragma unroll
    for (int kk = 0; kk < 2; kk++) {
      f16x8 af, bgf[2], bcf[2];
      {
        int row = waveR * 16 + (l & 15);
        int blk = (kk * 4 + (l >> 4)) ^ (row & 7);
        af = *(const f16x8*)&Asub[cur][row * 64 + blk * 8];
      }
#pragma unroll
      for (int j = 0; j < 2; j++) {
        int cl = waveC * 32 + j * 16 + (l & 15);
        int blk = (kk * 4 + (l >> 4)) ^ (cl & 7);
        bgf[j] = *(const f16x8*)&Bgs[cur][cl * 64 + blk * 8];
        bcf[j] = *(const f16x8*)&Bcs[cur][cl * 64 + blk * 8];
      }
#pragma unroll
      for (int j = 0; j < 2; j++) {
        accG[j] = __builtin_amdgcn_mfma_f32_16x16x32_f16(af, bgf[j], accG[j], 0, 0, 0);
        accC[j] = __builtin_amdgcn_mfma_f32_16x16x32_f16(af, bcf[j], accC[j], 0, 0, 0);
      }
    }
    if (kt + 1 < 24) {
      asm volatile("s_waitcnt vmcnt(0)" ::: "memory");
      __syncthreads();
      cur ^= 1;
    }
  }
  // epilogue: gates + h update
#pragma unroll
  for (int j = 0; j < 2; j++) {
    int col = colBase + waveC * 32 + j * 16 + (l & 15);
    float bG = bgr[z * 512 + col] + tp1 * vg2[z * 512 + col];
    float bC = bcr[z * 512 + col] + tp1 * vc2[z * 512 + col];
#pragma unroll
    for (int reg = 0; reg < 4; reg++) {
      int row = rowBase + waveR * 16 + ((l >> 4) << 2) + reg;
      float g = 1.f / (1.f + __expf(-(accG[j][reg] + bG)));
      float cd = tanhf(accC[j][reg] + bC);
      long hidx = ((long)z * 256 + row) * 512 + col;
      float h = h32[hidx];
      float nh = (1.f - g) * h + g * cd;
      h32[hidx] = nh;
      h16next[hidx] = (f16)nh;
    }
  }
}

// ---------------- classifier (fp32)
__global__ __launch_bounds__(256) void cls_kernel(
    const float* __restrict__ h32, const float* __restrict__ wcls,
    const float* __restrict__ bcls, float* __restrict__ out)
{
  __shared__ float As[2][512];
  int n = blockIdx.x >> 7, r0 = (blockIdx.x & 127) * 2;
  int t = threadIdx.x;
  for (int i = t; i < 1024; i += 256)
    As[i >> 9][i & 511] = h32[((long)(n * 256 + r0 + (i >> 9))) * 512 + (i & 511)];
  __syncthreads();
  int r = r0 + (t >> 7), c = t & 127;
  if (c < 100) {
    const float* wp = wcls + (long)n * 512 * 100 + c;
    const float* arow = As[t >> 7];
    float acc = bcls[n * 100 + c];
#pragma unroll 4
    for (int k = 0; k < 512; k++) acc = fmaf(arow[k], wp[k * 100], acc);
    out[((long)(n * 256 + r)) * 100 + c] = acc;
  }
}

extern "C" void kernel_launch(void* const* d_in, const int* in_sizes, int n_in,
                              void* d_out, int out_size, void* d_ws, size_t ws_size,
                              hipStream_t stream)
{
  (void)in_sizes; (void)n_in; (void)out_size;
  const float* x        = (const float*)d_in[0];
  const float* conv1_w  = (const float*)d_in[1];
  const float* conv1_b  = (const float*)d_in[2];
  const float* conv2_w  = (const float*)d_in[3];
  const float* conv2_b  = (const float*)d_in[4];
  const float* feat_w   = (const float*)d_in[5];
  const float* feat_b   = (const float*)d_in[6];
  const float* ctrl_wi  = (const float*)d_in[7];
  const float* ctrl_wh  = (const float*)d_in[8];
  const float* ctrl_bi  = (const float*)d_in[9];
  const float* ctrl_bh  = (const float*)d_in[10];
  const float* send_w   = (const float*)d_in[11];
  const float* send_b   = (const float*)d_in[12];
  const float* recv_w   = (const float*)d_in[13];
  const float* recv_b   = (const float*)d_in[14];
  const float* abias_w  = (const float*)d_in[15];
  const float* abias_b  = (const float*)d_in[16];
  const float* wq       = (const float*)d_in[17];
  const float* wk       = (const float*)d_in[18];
  const float* wv       = (const float*)d_in[19];
  const float* wo       = (const float*)d_in[20];
  const float* bo       = (const float*)d_in[21];
  const float* edge     = (const float*)d_in[22];
  const float* wr       = (const float*)d_in[23];
  const float* br       = (const float*)d_in[24];
  const float* wg       = (const float*)d_in[25];
  const float* bg       = (const float*)d_in[26];
  const float* wc       = (const float*)d_in[27];
  const float* bc       = (const float*)d_in[28];
  const float* wcls     = (const float*)d_in[29];
  const float* bcls     = (const float*)d_in[30];

  // ---- workspace layout
  float* f32b = (float*)d_ws;
  float* h32      = f32b;             // 1,048,576
  float* gi32     = f32b + 1048576;   //   393,216
  float* msgsum32 = f32b + 1441792;   // 1,048,576
  float* cs       = f32b + 2490368;   //   131,072
  float* bor32    = f32b + 2621440;   //     4,096
  float* bgr      = f32b + 2625536;   //     4,096
  float* vg2b     = f32b + 2629632;   //     4,096
  float* bcr      = f32b + 2633728;   //     4,096
  float* vc2b     = f32b + 2637824;   //     4,096
  f16* hb = (f16*)(f32b + 2641920);
  f16* pooled16 = hb;                 //   262,144
  f16* h16a     = hb + 262144;        // 1,048,576
  f16* h16b     = hb + 1310720;       // 1,048,576
  f16* feats16  = hb + 2359296;       // 1,048,576
  f16* msgsum16 = hb + 3407872;       // 1,048,576
  f16* qkv16    = hb + 4456448;       // 3,145,728
  f16* wqT      = hb + 7602176;       // 6,291,456 (wq|wk|wv)
  f16* wiT      = hb + 13893632;      //   786,432
  f16* featwT   = hb + 14680064;      //   524,288
  f16* wrT      = hb + 15204352;      // 2,097,152 (x0.125)
  f16* wgT      = hb + 17301504;      // 6,291,456
  f16* wcT      = hb + 23592960;      // 6,291,456
  f16* c2wp     = hb + 29884416;      //   589,824
  f16* wo16     = hb + 30474240;      // 2,097,152
  f16* P        = hb + 32571392;      // 2,097,152
  f16* P2       = hb + 34668544;      // 2,097,152 (copy of P for z=8..15)
  f16* WeffGT   = hb + 36765696;      // 2,097,152
  f16* WeffCT   = hb + 38862848;      // 2,097,152
  f16* w1p      = hb + 40960000;      //    16,384
  // total = 10,567,680 + 81,952,768 = 92,520,448 B
  if (ws_size < 92520448ull) return;

  f16* hbuf[2] = {h16a, h16b};

  // ---- one-time weight prep
  twmulti4_kernel<<<dim3(8, 8, 32), 256, 0, stream>>>(wq, wk, wv, ctrl_wi, wqT);
  twmulti2_kernel<<<dim3(8, 24, 16), 256, 0, stream>>>(wg, wc, wgT);
  tw64_kernel<<<dim3(8, 8, 8), 256, 0, stream>>>(wr, wrT, 512, 512, 0.125f);
  tw64_kernel<<<dim3(8, 2, 8), 256, 0, stream>>>(feat_w, featwT, 128, 512, 1.f);
  smallprep_kernel<<<3392, 256, 0, stream>>>(wo, wo16, conv2_w, c2wp, conv1_w, w1p);
  biascombo_kernel<<<8, 512, 0, stream>>>(wrT, bo, wgT, wcT, br, bg, bc,
                                          bor32, bgr, vg2b, bcr, vc2b);
  // P[c][m] = sum_k wo[c][k]*wr[k][m]/8  (mirror into P2 for z=8..15 reads)
  {
    SegsM s{};
    s.BT[0] = wrT; s.sBT[0] = 262144;
    s.o16[0] = P; s.o16b[0] = P2; s.sO16[0] = 262144; s.ldo16[0] = 512;
    gemmf16_kernel<<<dim3(8, 8, 8), 256, 0, stream>>>(wo16, 262144L, 512, s, 512);
  }
  // Weff{G,C}T[o][c] = sum_m wg/wc_r[m][o]*P[c][m]  (z=16 over wgT|wcT contiguous)
  {
    SegsM s{};
    s.BT[0] = P; s.sBT[0] = 262144;
    s.o16[0] = WeffGT; s.sO16[0] = 262144; s.ldo16[0] = 512;
    gemmf16_kernel<<<dim3(8, 8, 16), 256, 0, stream>>>(wgT + 1024, 786432L, 1536, s, 512);
  }

  // ---- feature extraction -> pooled16
  convfused_kernel<<<dim3(256, 8), 256, 0, stream>>>(x, w1p, conv1_b, c2wp, conv2_b, pooled16);

  // feats = relu(pooled @ feat_w + b) -> feats16; h-init -> h16a + h32
  {
    SegsM s{};
    s.BT[0] = featwT; s.sBT[0] = 65536; s.bias[0] = feat_b; s.sBias[0] = 512; s.act[0] = 1;
    s.o16[0] = feats16; s.o16b[0] = h16a; s.sO16[0] = 131072; s.ldo16[0] = 512;
    s.o32[0] = h32; s.sO32[0] = 131072; s.ldo32[0] = 512;
    gemmf16_kernel<<<dim3(8, 4, 8), 256, 0, stream>>>(pooled16, 32768L, 128, s, 128);
  }

  for (int step = 0; step < 3; step++) {
    // q|k|v (f16) + gi (f32) = h @ {wq,wk,wv,ctrl_wi}
    {
      SegsM s{};
      s.BT[0] = wqT;            s.sBT[0] = 262144;
      s.BT[1] = wqT + 2097152;  s.sBT[1] = 262144;
      s.BT[2] = wqT + 4194304;  s.sBT[2] = 262144;
      s.BT[3] = wiT;            s.sBT[3] = 98304;
      s.bias[3] = ctrl_bi; s.sBias[3] = 192;
      s.o16[0] = qkv16;        s.sO16[0] = 393216; s.ldo16[0] = 1536;
      s.o16[1] = qkv16 + 512;  s.sO16[1] = 393216; s.ldo16[1] = 1536;
      s.o16[2] = qkv16 + 1024; s.sO16[2] = 393216; s.ldo16[2] = 1536;
      s.o32[3] = gi32; s.sO32[3] = 49152; s.ldo32[3] = 192;
      gemmf16_kernel<<<dim3(27, 4, 8), 256, 0, stream>>>(hbuf[step & 1], 131072L, 512, s, 512);
    }
    step_kernel<<<256, 256, 0, stream>>>(
        qkv16, gi32, ctrl_wh, ctrl_bh, cs, send_w, send_b, recv_w, recv_b,
        abias_w, abias_b, edge, msgsum32, msgsum16, step);
    gatefused_kernel<<<dim3(8, 8, 8), 256, 0, stream>>>(
        hbuf[step & 1], feats16, msgsum16, wgT, wcT, WeffGT, WeffCT,
        bgr, vg2b, bcr, vc2b, h32, hbuf[(step + 1) & 1], (float)(step + 1));
  }
  cls_kernel<<<1024, 256, 0, stream>>>(h32, wcls, bcls, (float*)d_out);
}